// Round 4
// baseline (4829.993 us; speedup 1.0000x reference)
//
#include <hip/hip_runtime.h>
#include <math.h>

#define NH 8
#define DKH 256
#define SEQ 1024
#define BSZ 8
#define DMODEL 2048
#define DINNER 4096
#define DSTATE 16
#define DTRANK 128

#define MiB 1048576ULL

// ---------------- workspace byte offsets ----------------
// mamba phase
#define O_XZ    (0*MiB)                  // f32 8192x8192 (x cols 0..4095, z 4096..8191)
#define O_IMGH  (256*MiB)                // bf16 8192x2048 imgF hi
#define O_IMGL  (288*MiB)
#define O_WINTH (320*MiB)                // bf16 8192x2048  W_in^T hi
#define O_WINTL (352*MiB)
#define O_WCOMB (384*MiB)                // f32 2048x160
#define O_DBC   (384*MiB + 1310720ULL)   // f32 8192x160   (ends exactly at 409206784)
// after xz GEMM, [256,384) is reused:
#define O_DBCH  (256*MiB)                // bf16 8192x128 (dbc dt-rank cols)
#define O_DBCL  (259*MiB)
#define O_WDTH  (262*MiB)                // bf16 4096x128 (W_dt^T)
#define O_WDTL  (264*MiB)
#define O_XST   (256*MiB)                // f32 [8][4096][1024] xs transposed (after dt GEMM)
#define O_YH    (256*MiB)                // bf16 8192x4096 (after ycvt, over xsT)
#define O_YL    (320*MiB)
#define O_WOUTH (0*MiB)                  // bf16 2048x4096 (after ycvt)
#define O_WOUTL (16*MiB)
// dtT f32 [8][4096][1024] lives in d_out (128 MiB), dead before out1 GEMM writes
// attention phase (after out1)
#define A_IMGH  (0*MiB)
#define A_IMGL  (32*MiB)
#define A_WQH   (64*MiB)
#define A_WQL   (72*MiB)
#define A_WKH   (80*MiB)
#define A_WKL   (88*MiB)
#define A_WVH   (96*MiB)
#define A_WVL   (104*MiB)
#define A_WOH   (112*MiB)
#define A_WOL   (120*MiB)
#define A_QH    (128*MiB)                // bf16 8192x2048
#define A_QL    (160*MiB)
#define A_KH    (192*MiB)                // bf16 8192x2048 (natural layout == B^T for QK^T)
#define A_KL    (224*MiB)
#define A_VTH   (256*MiB)                // bf16 (b,h,dk,seq) = 64x256x1024
#define A_VTL   (288*MiB)
#define A_S     (320*MiB)                // 64 MiB: 16 batches x 1024 x 1024 f32 (chunked)
#define A_ATTH  (0*MiB)                  // bf16 8192x2048 (img freed by then)
#define A_ATTL  (32*MiB)

#define FLAG_BIAS 1
#define FLAG_SOFTPLUS 2
#define FLAG_KT 4
#define FLAG_BF16 8
#define FLAG_DTT 16

typedef __attribute__((ext_vector_type(8))) short bf16x8;
typedef __attribute__((ext_vector_type(4))) float f32x4;
typedef const void __attribute__((address_space(1))) gv_t;
typedef void __attribute__((address_space(3))) lv_t;

__device__ __forceinline__ unsigned short f2bf(float x) {
    unsigned u = __float_as_uint(x);
    unsigned r = u + 0x7FFFu + ((u >> 16) & 1u);
    return (unsigned short)(r >> 16);
}
__device__ __forceinline__ float bf2f(unsigned short h) {
    return __uint_as_float((unsigned)h << 16);
}

// fast silu: x * rcp(1+exp(-x))  (v_rcp_f32, ~1e-7 rel err)
__device__ __forceinline__ float fsilu(float x) {
    return x * __builtin_amdgcn_rcpf(1.f + __expf(-x));
}

// DPP butterfly add within 16-lane rows (no LDS pipe, no lgkmcnt)
template<int CTRL>
__device__ __forceinline__ float dppadd(float x) {
    return x + __int_as_float(__builtin_amdgcn_mov_dpp(
        __float_as_int(x), CTRL, 0xf, 0xf, true));
}

// ---------------- conversion kernels ----------------
__global__ __launch_bounds__(256) void cvt_hilo(
    const float* __restrict__ in, unsigned short* __restrict__ hi,
    unsigned short* __restrict__ lo, int n4)
{
    int i = blockIdx.x * 256 + threadIdx.x;
    if (i >= n4) return;
    float4 x = ((const float4*)in)[i];
    ushort4 h, l;
    h.x = f2bf(x.x); l.x = f2bf(x.x - bf2f(h.x));
    h.y = f2bf(x.y); l.y = f2bf(x.y - bf2f(h.y));
    h.z = f2bf(x.z); l.z = f2bf(x.z - bf2f(h.z));
    h.w = f2bf(x.w); l.w = f2bf(x.w - bf2f(h.w));
    ((ushort4*)hi)[i] = h;
    ((ushort4*)lo)[i] = l;
}

// W: K x N row-major f32  ->  T: N x K row-major bf16 hi/lo
__global__ __launch_bounds__(256) void tcvt(
    const float* __restrict__ W, unsigned short* __restrict__ Thi,
    unsigned short* __restrict__ Tlo, int K, int N)
{
    __shared__ float t[32][33];
    int tx = threadIdx.x & 31, ty = threadIdx.x >> 5;
    int k0 = blockIdx.y * 32, n0 = blockIdx.x * 32;
    #pragma unroll
    for (int i = 0; i < 32; i += 8)
        t[ty + i][tx] = W[(size_t)(k0 + ty + i) * N + n0 + tx];
    __syncthreads();
    #pragma unroll
    for (int i = 0; i < 32; i += 8) {
        float v = t[tx][ty + i];
        size_t o = (size_t)(n0 + ty + i) * K + k0 + tx;
        unsigned short h = f2bf(v);
        Thi[o] = h;
        Tlo[o] = f2bf(v - bf2f(h));
    }
}

// pack dbc dt-rank cols (0..127, lda=160) -> dense bf16 hi/lo 8192x128
__global__ __launch_bounds__(256) void pack_dbc128(
    const float* __restrict__ dbc, unsigned short* __restrict__ hi,
    unsigned short* __restrict__ lo)
{
    int i = blockIdx.x * 256 + threadIdx.x;   // 0 .. 8192*32-1
    int r = i >> 5, c4 = (i & 31) << 2;
    float4 x = *(const float4*)&dbc[(size_t)r * 160 + c4];
    ushort4 h, l;
    h.x = f2bf(x.x); l.x = f2bf(x.x - bf2f(h.x));
    h.y = f2bf(x.y); l.y = f2bf(x.y - bf2f(h.y));
    h.z = f2bf(x.z); l.z = f2bf(x.z - bf2f(h.z));
    h.w = f2bf(x.w); l.w = f2bf(x.w - bf2f(h.w));
    size_t o = ((size_t)r * 128 + c4) >> 2;
    ((ushort4*)hi)[o] = h;
    ((ushort4*)lo)[o] = l;
}

// y' in xz x-cols (row stride 8192), gate with silu(z) from z-cols; pack bf16 hi/lo 8192x4096
__global__ __launch_bounds__(256) void ycvt(
    const float* __restrict__ xz, unsigned short* __restrict__ hi,
    unsigned short* __restrict__ lo)
{
    int i = blockIdx.x * 256 + threadIdx.x;   // 0 .. 8192*1024-1
    int r = i >> 10, c4 = (i & 1023) << 2;
    float4 x = *(const float4*)&xz[(size_t)r * 8192 + c4];
    float4 z = *(const float4*)&xz[(size_t)r * 8192 + DINNER + c4];
    x.x *= fsilu(z.x); x.y *= fsilu(z.y);
    x.z *= fsilu(z.z); x.w *= fsilu(z.w);
    ushort4 h, l;
    h.x = f2bf(x.x); l.x = f2bf(x.x - bf2f(h.x));
    h.y = f2bf(x.y); l.y = f2bf(x.y - bf2f(h.y));
    h.z = f2bf(x.z); l.z = f2bf(x.z - bf2f(h.z));
    h.w = f2bf(x.w); l.w = f2bf(x.w - bf2f(h.w));
    size_t o = ((size_t)r * 4096 + c4) >> 2;
    ((ushort4*)hi)[o] = h;
    ((ushort4*)lo)[o] = l;
}

// ---------------- MFMA split GEMM ----------------
// C(MxN,f32) = (Ahi+Alo)(Bhi) + Ahi*Blo;  A: MxK row-major bf16, B given as B^T: NxK row-major bf16
// LDS bank-swizzle (both-sides, rule #21): the 16B chunk index within each row's
// 64B k-block is XOR'd with ((row>>1)&3) -- applied on the GLOBAL source address
// (global_load_lds writes LDS linearly) and on the fragment ds_read offset.
__device__ __forceinline__ void gload16(const unsigned short* g, unsigned short* l) {
    __builtin_amdgcn_global_load_lds((gv_t*)g, (lv_t*)l, 16, 0, 0);
}

__global__ __launch_bounds__(256) void gemm_mfma3(
    const unsigned short* __restrict__ Ahi, const unsigned short* __restrict__ Alo,
    const unsigned short* __restrict__ Bhi, const unsigned short* __restrict__ Blo,
    const float* __restrict__ bias, float* __restrict__ C,
    unsigned short* __restrict__ Chi, unsigned short* __restrict__ Clo,
    int M, int N, int K, int flags)
{
    __shared__ unsigned short sAh[128*32], sAl[128*32], sBh[128*32], sBl[128*32];
    int tid = threadIdx.x;
    int lane = tid & 63, wv = tid >> 6;
    int wm = wv >> 1, wn = wv & 1;

    // bijective XCD swizzle: each XCD gets a contiguous band of output tiles
    int nbx = gridDim.x;
    int lin = blockIdx.y * nbx + blockIdx.x;
    int cpx = (nbx * gridDim.y) >> 3;        // all grids have nwg % 8 == 0
    int swz = (lin & 7) * cpx + (lin >> 3);
    int bm = (swz / nbx) * 128, bn = (swz % nbx) * 128;

    int rbase = wv * 32;
    int srow = lane >> 2;
    int scol = (((lane & 3) ^ ((srow >> 1) & 3)) << 3);   // swizzled source chunk
    const size_t aoff0 = (size_t)(bm + rbase + srow) * K + scol;
    const size_t aoff1 = aoff0 + (size_t)16 * K;
    const size_t boff0 = (size_t)(bn + rbase + srow) * K + scol;
    const size_t boff1 = boff0 + (size_t)16 * K;
    unsigned short* lA0 = &sAh[rbase * 32];
    unsigned short* lA1 = &sAh[(rbase + 16) * 32];
    unsigned short* lAl0 = &sAl[rbase * 32];
    unsigned short* lAl1 = &sAl[(rbase + 16) * 32];
    unsigned short* lB0 = &sBh[rbase * 32];
    unsigned short* lB1 = &sBh[(rbase + 16) * 32];
    unsigned short* lBl0 = &sBl[rbase * 32];
    unsigned short* lBl1 = &sBl[(rbase + 16) * 32];

    f32x4 acc[4][4];
    #pragma unroll
    for (int i = 0; i < 4; i++)
        #pragma unroll
        for (int j = 0; j < 4; j++)
            acc[i][j] = (f32x4){0.f, 0.f, 0.f, 0.f};

    int fr = lane & 15;
    int q8 = (((lane >> 4) ^ ((fr >> 1) & 3)) << 3);      // swizzled read chunk

    for (int k0 = 0; k0 < K; k0 += 32) {
        gload16(Ahi + aoff0 + k0, lA0);
        gload16(Ahi + aoff1 + k0, lA1);
        gload16(Alo + aoff0 + k0, lAl0);
        gload16(Alo + aoff1 + k0, lAl1);
        gload16(Bhi + boff0 + k0, lB0);
        gload16(Bhi + boff1 + k0, lB1);
        gload16(Blo + boff0 + k0, lBl0);
        gload16(Blo + boff1 + k0, lBl1);
        __syncthreads();

        bf16x8 ah[4], al[4], bh[4], bl[4];
        #pragma unroll
        for (int t = 0; t < 4; t++) {
            ah[t] = *(const bf16x8*)&sAh[(wm * 64 + t * 16 + fr) * 32 + q8];
            al[t] = *(const bf16x8*)&sAl[(wm * 64 + t * 16 + fr) * 32 + q8];
            bh[t] = *(const bf16x8*)&sBh[(wn * 64 + t * 16 + fr) * 32 + q8];
            bl[t] = *(const bf16x8*)&sBl[(wn * 64 + t * 16 + fr) * 32 + q8];
        }
        #pragma unroll
        for (int i = 0; i < 4; i++)
            #pragma unroll
            for (int j = 0; j < 4; j++) {
                acc[i][j] = __builtin_amdgcn_mfma_f32_16x16x32_bf16(ah[i], bh[j], acc[i][j], 0, 0, 0);
                acc[i][j] = __builtin_amdgcn_mfma_f32_16x16x32_bf16(al[i], bh[j], acc[i][j], 0, 0, 0);
                acc[i][j] = __builtin_amdgcn_mfma_f32_16x16x32_bf16(ah[i], bl[j], acc[i][j], 0, 0, 0);
            }
        __syncthreads();
    }

    // epilogue: C/D layout col=lane&15, row=(lane>>4)*4+reg
    int q4 = (lane >> 4) * 4, c16 = lane & 15;
    #pragma unroll
    for (int i = 0; i < 4; i++)
        #pragma unroll
        for (int j = 0; j < 4; j++) {
            f32x4 v = acc[i][j];
            int col = bn + wn * 64 + j * 16 + c16;
            float bv = (flags & FLAG_BIAS) ? bias[col] : 0.f;
            #pragma unroll
            for (int r = 0; r < 4; r++) {
                int row = bm + wm * 64 + i * 16 + q4 + r;
                float val = v[r] + bv;
                if (flags & FLAG_DTT) {
                    // softplus, write transposed f32 [b][d][t]
                    float sp = (val > 20.f) ? val : log1pf(__expf(val));
                    C[((size_t)(row >> 10) * 4096 + col) * 1024 + (row & 1023)] = sp;
                } else if (flags & FLAG_BF16) {
                    size_t o;
                    if (flags & FLAG_KT) {
                        int bi = row >> 10, jj = row & 1023;
                        int hd = col >> 8, dk2 = col & 255;
                        o = ((size_t)((bi * NH + hd) * DKH + dk2)) * SEQ + jj;
                    } else {
                        o = (size_t)row * N + col;
                    }
                    unsigned short hv = f2bf(val);
                    Chi[o] = hv;
                    Clo[o] = f2bf(val - bf2f(hv));
                } else if (flags & FLAG_KT) {
                    int bi = row >> 10, jj = row & 1023;
                    int hd = col >> 8, dk2 = col & 255;
                    C[((size_t)((bi * NH + hd) * DKH + dk2)) * SEQ + jj] = val;
                } else {
                    C[(size_t)row * N + col] = val;
                }
            }
        }
}

// ---------------- batched split GEMM for attention ----------------
__global__ __launch_bounds__(256) void gemm_att3(
    const unsigned short* __restrict__ Ahi, const unsigned short* __restrict__ Alo,
    const unsigned short* __restrict__ Bhi, const unsigned short* __restrict__ Blo,
    float* __restrict__ Cf, unsigned short* __restrict__ Ohi, unsigned short* __restrict__ Olo,
    int K, int lda, int ldb, int chunk_base, int mode)
{
    __shared__ unsigned short sAh[128*32], sAl[128*32], sBh[128*32], sBl[128*32];
    int tid = threadIdx.x;
    int lane = tid & 63, wv = tid >> 6;
    int wm = wv >> 1, wn = wv & 1;
    int bm = blockIdx.y * 128, bn = blockIdx.x * 128;
    int z = blockIdx.z;
    int g = chunk_base + z;

    size_t abase, bbase;
    if (mode == 0) {
        abase = (size_t)(g >> 3) * (1024 * 2048) + (size_t)(g & 7) * 256;
        bbase = abase;
    } else {
        abase = (size_t)z * (1024 * 2048);
        bbase = (size_t)g * (256 * 1024);
    }

    int rbase = wv * 32;
    int srow = lane >> 2;
    int scol = (((lane & 3) ^ ((srow >> 1) & 3)) << 3);   // swizzled source chunk
    const size_t aoff0 = abase + (size_t)(bm + rbase + srow) * lda + scol;
    const size_t aoff1 = aoff0 + (size_t)16 * lda;
    const size_t boff0 = bbase + (size_t)(bn + rbase + srow) * ldb + scol;
    const size_t boff1 = boff0 + (size_t)16 * ldb;
    unsigned short* lA0 = &sAh[rbase * 32];
    unsigned short* lA1 = &sAh[(rbase + 16) * 32];
    unsigned short* lAl0 = &sAl[rbase * 32];
    unsigned short* lAl1 = &sAl[(rbase + 16) * 32];
    unsigned short* lB0 = &sBh[rbase * 32];
    unsigned short* lB1 = &sBh[(rbase + 16) * 32];
    unsigned short* lBl0 = &sBl[rbase * 32];
    unsigned short* lBl1 = &sBl[(rbase + 16) * 32];

    f32x4 acc[4][4];
    #pragma unroll
    for (int i = 0; i < 4; i++)
        #pragma unroll
        for (int j = 0; j < 4; j++)
            acc[i][j] = (f32x4){0.f, 0.f, 0.f, 0.f};

    int fr = lane & 15;
    int q8 = (((lane >> 4) ^ ((fr >> 1) & 3)) << 3);      // swizzled read chunk

    for (int k0 = 0; k0 < K; k0 += 32) {
        gload16(Ahi + aoff0 + k0, lA0);
        gload16(Ahi + aoff1 + k0, lA1);
        gload16(Alo + aoff0 + k0, lAl0);
        gload16(Alo + aoff1 + k0, lAl1);
        gload16(Bhi + boff0 + k0, lB0);
        gload16(Bhi + boff1 + k0, lB1);
        gload16(Blo + boff0 + k0, lBl0);
        gload16(Blo + boff1 + k0, lBl1);
        __syncthreads();

        bf16x8 ah[4], al[4], bh[4], bl[4];
        #pragma unroll
        for (int t = 0; t < 4; t++) {
            ah[t] = *(const bf16x8*)&sAh[(wm * 64 + t * 16 + fr) * 32 + q8];
            al[t] = *(const bf16x8*)&sAl[(wm * 64 + t * 16 + fr) * 32 + q8];
            bh[t] = *(const bf16x8*)&sBh[(wn * 64 + t * 16 + fr) * 32 + q8];
            bl[t] = *(const bf16x8*)&sBl[(wn * 64 + t * 16 + fr) * 32 + q8];
        }
        #pragma unroll
        for (int i = 0; i < 4; i++)
            #pragma unroll
            for (int j = 0; j < 4; j++) {
                acc[i][j] = __builtin_amdgcn_mfma_f32_16x16x32_bf16(ah[i], bh[j], acc[i][j], 0, 0, 0);
                acc[i][j] = __builtin_amdgcn_mfma_f32_16x16x32_bf16(al[i], bh[j], acc[i][j], 0, 0, 0);
                acc[i][j] = __builtin_amdgcn_mfma_f32_16x16x32_bf16(ah[i], bl[j], acc[i][j], 0, 0, 0);
            }
        __syncthreads();
    }

    int q4 = (lane >> 4) * 4, c16 = lane & 15;
    #pragma unroll
    for (int i = 0; i < 4; i++)
        #pragma unroll
        for (int j = 0; j < 4; j++) {
            f32x4 v = acc[i][j];
            int col = bn + wn * 64 + j * 16 + c16;
            #pragma unroll
            for (int r = 0; r < 4; r++) {
                int row = bm + wm * 64 + i * 16 + q4 + r;
                float val = v[r];
                if (mode == 0) {
                    Cf[(size_t)z * (1024 * 1024) + (size_t)row * 1024 + col] = val * 0.0625f;
                } else {
                    size_t o = ((size_t)((g >> 3) * 1024 + row)) * 2048 + (size_t)(g & 7) * 256 + col;
                    unsigned short hv = f2bf(val);
                    Ohi[o] = hv;
                    Olo[o] = f2bf(val - bf2f(hv));
                }
            }
        }
}

// ---------------- row softmax, in-place f32 -> bf16 hi/lo ----------------
__global__ __launch_bounds__(256) void softmax_rows(float* __restrict__ S)
{
    int lane = threadIdx.x & 63, wid = threadIdx.x >> 6;
    size_t row = (size_t)blockIdx.x * 4 + wid;
    float* rp = S + row * 1024;

    float4 x[4];
    float m = -1e30f;
    #pragma unroll
    for (int w = 0; w < 4; w++) {
        x[w] = *(const float4*)&rp[w * 256 + lane * 4];
        m = fmaxf(m, fmaxf(fmaxf(x[w].x, x[w].y), fmaxf(x[w].z, x[w].w)));
    }
    #pragma unroll
    for (int off = 1; off < 64; off <<= 1) m = fmaxf(m, __shfl_xor(m, off));

    float s = 0.f;
    #pragma unroll
    for (int w = 0; w < 4; w++) {
        x[w].x = __expf(x[w].x - m);
        x[w].y = __expf(x[w].y - m);
        x[w].z = __expf(x[w].z - m);
        x[w].w = __expf(x[w].w - m);
        s += x[w].x + x[w].y + x[w].z + x[w].w;
    }
    #pragma unroll
    for (int off = 1; off < 64; off <<= 1) s += __shfl_xor(s, off);
    float inv = 1.f / s;

    unsigned short* hp = (unsigned short*)rp;
    unsigned short* lp = hp + 1024;
    #pragma unroll
    for (int w = 0; w < 4; w++) {
        float a0 = x[w].x * inv, a1 = x[w].y * inv;
        float a2 = x[w].z * inv, a3 = x[w].w * inv;
        ushort4 h, l;
        h.x = f2bf(a0); l.x = f2bf(a0 - bf2f(h.x));
        h.y = f2bf(a1); l.y = f2bf(a1 - bf2f(h.y));
        h.z = f2bf(a2); l.z = f2bf(a2 - bf2f(h.z));
        h.w = f2bf(a3); l.w = f2bf(a3 - bf2f(h.w));
        int c = w * 256 + lane * 4;
        *(ushort4*)&hp[c] = h;
        *(ushort4*)&lp[c] = l;
    }
}

// ---------------- fp32 GEMM (small shapes) ----------------
#define BM 64
#define BN 64
#define BK 16
__global__ __launch_bounds__(256) void gemm_f32(
    const float* __restrict__ A, const float* __restrict__ B,
    const float* __restrict__ bias, float* __restrict__ C,
    int M, int N, int K, int lda, int ldb, int ldc, int flags)
{
    __shared__ float As[BK][BM + 4];
    __shared__ float Bs[BK][BN + 4];
    int tid = threadIdx.x;
    int tm = tid >> 4, tn = tid & 15;
    int bm = blockIdx.y * BM, bn = blockIdx.x * BN;
    float acc[4][4] = {};

    for (int k0 = 0; k0 < K; k0 += BK) {
        #pragma unroll
        for (int i = 0; i < 4; i++) {
            int idx = tid + i * 256;
            int r = idx >> 4, c = idx & 15;
            int gr = bm + r, gc = k0 + c;
            float v = 0.f;
            if (gr < M && gc < K) v = A[(size_t)gr * lda + gc];
            As[c][r] = v;
        }
        #pragma unroll
        for (int i = 0; i < 4; i++) {
            int idx = tid + i * 256;
            int r = idx >> 6, c = idx & 63;
            int gr = k0 + r, gc = bn + c;
            float v = 0.f;
            if (gr < K && gc < N) v = B[(size_t)gr * ldb + gc];
            Bs[r][c] = v;
        }
        __syncthreads();
        #pragma unroll
        for (int kk = 0; kk < BK; kk++) {
            float4 a4 = *(const float4*)&As[kk][tm * 4];
            float4 b4 = *(const float4*)&Bs[kk][tn * 4];
            float av[4] = {a4.x, a4.y, a4.z, a4.w};
            float bv[4] = {b4.x, b4.y, b4.z, b4.w};
            #pragma unroll
            for (int i = 0; i < 4; i++)
                #pragma unroll
                for (int j = 0; j < 4; j++)
                    acc[i][j] += av[i] * bv[j];
        }
        __syncthreads();
    }

    #pragma unroll
    for (int i = 0; i < 4; i++) {
        int row = bm + tm * 4 + i;
        if (row >= M) continue;
        #pragma unroll
        for (int j = 0; j < 4; j++) {
            int col = bn + tn * 4 + j;
            if (col >= N) continue;
            float val = acc[i][j];
            if (flags & FLAG_BIAS) val += bias[col];
            if (flags & FLAG_SOFTPLUS) val = (val > 20.f) ? val : log1pf(__expf(val));
            C[(size_t)row * ldc + col] = val;
        }
    }
}

// ---------------- BC repack: dbc[row][128+n],[144+n] -> interleaved pairs at cols 0..31 ----------------
__global__ __launch_bounds__(256) void repack_bc(float* __restrict__ dbc)
{
    int i = blockIdx.x * 256 + threadIdx.x;   // 0 .. 8192*16-1
    int n = i & 15;
    int row = i >> 4;
    float B = dbc[(size_t)row * 160 + DTRANK + n];
    float C = dbc[(size_t)row * 160 + DTRANK + DSTATE + n];
    float2 p; p.x = B; p.y = C;
    ((float2*)&dbc[(size_t)row * 160])[n] = p;
}

// ---------------- conv+silu transpose: x[t][d] -> xsT[b][d][t] ----------------
// grid (64 d-tiles, 128 t-tiles), 256 threads, 64x64 tile
__global__ __launch_bounds__(256) void conv_prep(
    const float* __restrict__ xz, float* __restrict__ xsT,
    const float* __restrict__ conv_w, const float* __restrict__ conv_b)
{
    __shared__ float sx[67][68];
    int tid = threadIdx.x;
    int d0 = blockIdx.x * 64;
    int t0 = blockIdx.y * 64;           // global row index (b*1024 + tloc)
    int tloc0 = t0 & 1023;

    // load rows t0-3 .. t0+63 (67 rows x 64 d), zero halo at sequence start
    int lr = tid >> 2;                  // 0..63
    int lc = (tid & 3) * 16;            // 0,16,32,48
    for (int rr = lr; rr < 67; rr += 64) {
        int tg = t0 - 3 + rr;
        bool ok = (tloc0 != 0) || (rr >= 3);
        #pragma unroll
        for (int c = 0; c < 16; c += 4) {
            float4 v = ok ? *(const float4*)&xz[(size_t)tg * 8192 + d0 + lc + c]
                          : (float4){0.f, 0.f, 0.f, 0.f};
            *(float4*)&sx[rr][lc + c] = v;
        }
    }
    __syncthreads();

    // compute: thread -> d = d0 + (tid>>2), t quarter = (tid&3)*16
    int dr = tid >> 2;
    int tq = (tid & 3) * 16;
    int d = d0 + dr;
    float cw0 = conv_w[d * 4 + 0], cw1 = conv_w[d * 4 + 1];
    float cw2 = conv_w[d * 4 + 2], cw3 = conv_w[d * 4 + 3];
    float cb = conv_b[d];

    float x0 = sx[tq + 0][dr], x1 = sx[tq + 1][dr], x2 = sx[tq + 2][dr];
    float o[16];
    #pragma unroll
    for (int tt = 0; tt < 16; tt++) {
        float x3 = sx[tq + tt + 3][dr];
        float xc = cw0 * x0 + cw1 * x1 + cw2 * x2 + cw3 * x3 + cb;
        o[tt] = fsilu(xc);
        x0 = x1; x1 = x2; x2 = x3;
    }
    size_t ob = ((size_t)(t0 >> 10) * 4096 + d) * 1024 + tloc0 + tq;
    #pragma unroll
    for (int c = 0; c < 16; c += 4)
        *(float4*)&xsT[ob + c] = (float4){o[c], o[c+1], o[c+2], o[c+3]};
}

// ---------------- lean mamba scan (transposed streams, LDS chunked) ----------------
// xsT/dtT: f32 [8][4096][1024]; bc: packed (B,C) pairs at dbc cols 0..31.
// writes y' = p + dsk*xs (pre-gate) into xz x-cols [t][d].
__global__ __launch_bounds__(256) void mamba_scan(
    float* __restrict__ xz, const float* __restrict__ dtT,
    const float* __restrict__ bc, const float* __restrict__ A_log,
    const float* __restrict__ D_skip, const float* __restrict__ xsT)
{
    __shared__ float sxs[16 * 68];
    __shared__ float sdt[16 * 68];
    __shared__ float sbc[64 * 32];

    int tid = threadIdx.x;
    int n = tid & 15;
    int dd = tid >> 4;
    int gb = blockIdx.x;
    int b = gb >> 8;
    int d0 = (gb & 255) << 4;
    int d = d0 + dd;

    float A_n = -__expf(A_log[d * DSTATE + n]);
    float dsk = D_skip[d];
    float h = 0.f;

    size_t baseT = ((size_t)b * 4096 + d0) * 1024;
    size_t rowbc = (size_t)b * SEQ * 160;
    size_t rowx  = (size_t)b * SEQ * 8192 + d;

    int sr = tid >> 4;            // 0..15: d-row for xs/dt staging
    int sc = (tid & 15) * 4;      // float4 col
    int br = tid >> 2;            // 0..63: t-row for bc staging
    int bq = (tid & 3) * 8;

    for (int t0 = 0; t0 < SEQ; t0 += 64) {
        float4 vx = *(const float4*)&xsT[baseT + (size_t)sr * 1024 + t0 + sc];
        float4 vd = *(const float4*)&dtT[baseT + (size_t)sr * 1024 + t0 + sc];
        float4 v0 = *(const float4*)&bc[rowbc + (size_t)(t0 + br) * 160 + bq];
        float4 v1 = *(const float4*)&bc[rowbc + (size_t)(t0 + br) * 160 + bq + 4];
        __syncthreads();
        *(float4*)&sxs[sr * 68 + sc] = vx;
        *(float4*)&sdt[sr * 68 + sc] = vd;
        *(float4*)&sbc[br * 32 + bq] = v0;
        *(float4*)&sbc[br * 32 + bq + 4] = v1;
        __syncthreads();

        #pragma unroll 4
        for (int tl = 0; tl < 64; tl++) {
            float xv  = sxs[dd * 68 + tl];
            float dtv = sdt[dd * 68 + tl];
            float2 bcv = *(const float2*)&sbc[tl * 32 + 2 * n];
            float dA = __expf(dtv * A_n);
            h = dA * h + (dtv * xv) * bcv.x;
            float p = h * bcv.y;
            p = dppadd<0xB1>(p);    // quad_perm xor1
            p = dppadd<0x4E>(p);    // quad_perm xor2
            p = dppadd<0x141>(p);   // row_half_mirror
            p = dppadd<0x140>(p);   // row_mirror
            if (n == 0)
                xz[rowx + (size_t)(t0 + tl) * 8192] = p + dsk * xv;
        }
    }
}

// ---------------- launcher ----------------
extern "C" void kernel_launch(void* const* d_in, const int* in_sizes, int n_in,
                              void* d_out, int out_size, void* d_ws, size_t ws_size,
                              hipStream_t stream) {
    const float* imgF   = (const float*)d_in[0];
    const float* kf     = (const float*)d_in[1];
    const float* Wq     = (const float*)d_in[2];
    const float* bq     = (const float*)d_in[3];
    const float* Wk     = (const float*)d_in[4];
    const float* bk     = (const float*)d_in[5];
    const float* Wv     = (const float*)d_in[6];
    const float* bv     = (const float*)d_in[7];
    const float* Wo     = (const float*)d_in[8];
    const float* bo     = (const float*)d_in[9];
    const float* W_in   = (const float*)d_in[10];
    const float* conv_w = (const float*)d_in[11];
    const float* conv_b = (const float*)d_in[12];
    const float* W_extra= (const float*)d_in[13];
    const float* W_xproj= (const float*)d_in[14];
    const float* W_dt   = (const float*)d_in[15];
    const float* b_dt   = (const float*)d_in[16];
    const float* A_log  = (const float*)d_in[17];
    const float* D_skip = (const float*)d_in[18];
    const float* W_out  = (const float*)d_in[19];
    float* out = (float*)d_out;
    char* W = (char*)d_ws;

    #define WS_F(off) ((float*)(W + (off)))
    #define WS_U(off) ((unsigned short*)(W + (off)))

    dim3 blk(256);
    auto gg = [](int M, int N) { return dim3((N + BN - 1) / BN, (M + BM - 1) / BM); };

    // ===== mamba phase =====
    // imgF -> bf16 hi/lo
    cvt_hilo<<<dim3(16384), blk, 0, stream>>>(imgF, WS_U(O_IMGH), WS_U(O_IMGL), 4194304);
    // W_in (2048x8192) -> W_in^T hi/lo
    tcvt<<<dim3(8192/32, 2048/32), blk, 0, stream>>>(W_in, WS_U(O_WINTH), WS_U(O_WINTL), 2048, 8192);
    // xz = imgF @ W_in   (M=8192, N=8192, K=2048)
    gemm_mfma3<<<dim3(64, 64), blk, 0, stream>>>(WS_U(O_IMGH), WS_U(O_IMGL),
        WS_U(O_WINTH), WS_U(O_WINTL), nullptr, WS_F(O_XZ), nullptr, nullptr,
        8192, 8192, 2048, 0);
    // Wcomb = W_extra @ W_xproj   (2048x160, K=4096)
    gemm_f32<<<gg(2048, 160), blk, 0, stream>>>(W_extra, W_xproj, nullptr, WS_F(O_WCOMB),
        2048, 160, 4096, 4096, 160, 160, 0);
    // dbc = kf @ Wcomb
    gemm_f32<<<gg(8192, 160), blk, 0, stream>>>(kf, WS_F(O_WCOMB), nullptr, WS_F(O_DBC),
        8192, 160, 2048, 2048, 160, 160, 0);
    // pack dbc dt-rank cols -> bf16 hi/lo (imgh region is dead now)
    pack_dbc128<<<dim3(1024), blk, 0, stream>>>(WS_F(O_DBC), WS_U(O_DBCH), WS_U(O_DBCL));
    // pack (B,C) pairs into dead dt-rank cols of dbc
    repack_bc<<<dim3(512), blk, 0, stream>>>(WS_F(O_DBC));
    // W_dt (128x4096) -> W_dt^T hi/lo
    tcvt<<<dim3(4096/32, 128/32), blk, 0, stream>>>(W_dt, WS_U(O_WDTH), WS_U(O_WDTL), 128, 4096);
    // dtT = softplus(dbc128 @ W_dt + b_dt) transposed [b][d][t] -> d_out
    gemm_mfma3<<<dim3(32, 64), blk, 0, stream>>>(WS_U(O_DBCH), WS_U(O_DBCL),
        WS_U(O_WDTH), WS_U(O_WDTL), b_dt, out, nullptr, nullptr,
        8192, 4096, 128, FLAG_BIAS | FLAG_DTT);
    // xsT = silu(conv(x)) transposed [b][d][t]  (clobbers dbc128/wdt copies - dead)
    conv_prep<<<dim3(64, 128), blk, 0, stream>>>(WS_F(O_XZ), WS_F(O_XST), conv_w, conv_b);
    // lean scan: y' -> xz x-cols
    mamba_scan<<<dim3(2048), blk, 0, stream>>>(WS_F(O_XZ), out, WS_F(O_DBC),
        A_log, D_skip, WS_F(O_XST));
    // y = y' * silu(z) -> bf16 hi/lo (over xsT - dead)
    ycvt<<<dim3(32768), blk, 0, stream>>>(WS_F(O_XZ), WS_U(O_YH), WS_U(O_YL));
    // W_out (4096x2048) -> W_out^T hi/lo (xz dead)
    tcvt<<<dim3(2048/32, 4096/32), blk, 0, stream>>>(W_out, WS_U(O_WOUTH), WS_U(O_WOUTL), 4096, 2048);
    // out1 = y @ W_out   (M=8192, N=2048, K=4096)  (dtT in d_out dead)
    gemm_mfma3<<<dim3(16, 64), blk, 0, stream>>>(WS_U(O_YH), WS_U(O_YL),
        WS_U(O_WOUTH), WS_U(O_WOUTL), nullptr, out + 16777216, nullptr, nullptr,
        8192, 2048, 4096, 0);

    // ===== attention phase =====
    cvt_hilo<<<dim3(16384), blk, 0, stream>>>(imgF, WS_U(A_IMGH), WS_U(A_IMGL), 4194304);
    tcvt<<<dim3(64, 64), blk, 0, stream>>>(Wq, WS_U(A_WQH), WS_U(A_WQL), 2048, 2048);
    tcvt<<<dim3(64, 64), blk, 0, stream>>>(Wk, WS_U(A_WKH), WS_U(A_WKL), 2048, 2048);
    tcvt<<<dim3(64, 64), blk, 0, stream>>>(Wv, WS_U(A_WVH), WS_U(A_WVL), 2048, 2048);
    tcvt<<<dim3(64, 64), blk, 0, stream>>>(Wo, WS_U(A_WOH), WS_U(A_WOL), 2048, 2048);
    // q = imgF @ Wq + bq  -> bf16 hi/lo 8192x2048
    gemm_mfma3<<<dim3(16, 64), blk, 0, stream>>>(WS_U(A_IMGH), WS_U(A_IMGL),
        WS_U(A_WQH), WS_U(A_WQL), bq, nullptr, WS_U(A_QH), WS_U(A_QL),
        8192, 2048, 2048, FLAG_BIAS | FLAG_BF16);
    // k = imgF @ Wk + bk  -> bf16 hi/lo 8192x2048 (natural layout == B^T for S)
    gemm_mfma3<<<dim3(16, 64), blk, 0, stream>>>(WS_U(A_IMGH), WS_U(A_IMGL),
        WS_U(A_WKH), WS_U(A_WKL), bk, nullptr, WS_U(A_KH), WS_U(A_KL),
        8192, 2048, 2048, FLAG_BIAS | FLAG_BF16);
    // v^T = (imgF @ Wv + bv) transposed per (b,h) -> bf16 hi/lo (b,h,dk,seq)
    gemm_mfma3<<<dim3(16, 64), blk, 0, stream>>>(WS_U(A_IMGH), WS_U(A_IMGL),
        WS_U(A_WVH), WS_U(A_WVL), bv, nullptr, WS_U(A_VTH), WS_U(A_VTL),
        8192, 2048, 2048, FLAG_BIAS | FLAG_BF16 | FLAG_KT);
    // chunked attention: 4 chunks x 16 (b,h) batches, 64 MiB score buffer
    for (int c = 0; c < 4; c++) {
        gemm_att3<<<dim3(8, 8, 16), blk, 0, stream>>>(WS_U(A_QH), WS_U(A_QL),
            WS_U(A_KH), WS_U(A_KL), WS_F(A_S), nullptr, nullptr,
            256, 2048, 2048, c * 16, 0);
        softmax_rows<<<dim3(4096), blk, 0, stream>>>(WS_F(A_S));
        gemm_att3<<<dim3(2, 8, 16), blk, 0, stream>>>(
            (unsigned short*)WS_F(A_S), (unsigned short*)WS_F(A_S) + 1024,
            WS_U(A_VTH), WS_U(A_VTL), nullptr, WS_U(A_ATTH), WS_U(A_ATTL),
            1024, 2048, 1024, c * 16, 1);
    }
    // out0 = att @ Wo + bo
    gemm_mfma3<<<dim3(16, 64), blk, 0, stream>>>(WS_U(A_ATTH), WS_U(A_ATTL),
        WS_U(A_WOH), WS_U(A_WOL), bo, out, nullptr, nullptr,
        8192, 2048, 2048, FLAG_BIAS);
}

// Round 5
// 4810.827 us; speedup vs baseline: 1.0040x; 1.0040x over previous
//
#include <hip/hip_runtime.h>
#include <math.h>

#define NH 8
#define DKH 256
#define SEQ 1024
#define BSZ 8
#define DMODEL 2048
#define DINNER 4096
#define DSTATE 16
#define DTRANK 128

#define MiB 1048576ULL

// ---------------- workspace byte offsets ----------------
// mamba phase
#define O_XZ    (0*MiB)                  // f32 8192x8192 (x cols 0..4095, z 4096..8191)
#define O_IMGH  (256*MiB)                // bf16 8192x2048 imgF hi
#define O_IMGL  (288*MiB)
#define O_WINTH (320*MiB)                // bf16 8192x2048  W_in^T hi
#define O_WINTL (352*MiB)
#define O_WCOMB (384*MiB)                // f32 2048x160
#define O_DBC   (384*MiB + 1310720ULL)   // f32 8192x160   (ends exactly at 409206784)
// after xz GEMM, [256,384) is reused:
#define O_DBCH  (256*MiB)                // bf16 8192x128 (dbc dt-rank cols)
#define O_DBCL  (259*MiB)
#define O_WDTH  (262*MiB)                // bf16 4096x128 (W_dt^T)
#define O_WDTL  (264*MiB)
#define O_XST   (256*MiB)                // f32 [8][4096][1024] xs transposed (after dt GEMM)
#define O_YH    (256*MiB)                // bf16 8192x4096 (after ycvt, over xsT)
#define O_YL    (320*MiB)
#define O_WOUTH (0*MiB)                  // bf16 2048x4096 (after ycvt)
#define O_WOUTL (16*MiB)
// dtT f32 [8][4096][1024] lives in d_out (128 MiB), dead before out1 GEMM writes
// attention phase (after out1)
#define A_IMGH  (0*MiB)
#define A_IMGL  (32*MiB)
#define A_WQH   (64*MiB)
#define A_WQL   (72*MiB)
#define A_WKH   (80*MiB)
#define A_WKL   (88*MiB)
#define A_WVH   (96*MiB)
#define A_WVL   (104*MiB)
#define A_WOH   (112*MiB)
#define A_WOL   (120*MiB)
#define A_QH    (128*MiB)                // bf16 8192x2048
#define A_QL    (160*MiB)
#define A_KH    (192*MiB)                // bf16 8192x2048 (natural layout == B^T for QK^T)
#define A_KL    (224*MiB)
#define A_VTH   (256*MiB)                // bf16 (b,h,dk,seq) = 64x256x1024
#define A_VTL   (288*MiB)
#define A_S     (320*MiB)                // 64 MiB: 16 batches x 1024 x 1024 f32 (chunked)
#define A_ATTH  (0*MiB)                  // bf16 8192x2048 (img freed by then)
#define A_ATTL  (32*MiB)

#define FLAG_BIAS 1
#define FLAG_SOFTPLUS 2
#define FLAG_KT 4
#define FLAG_BF16 8
#define FLAG_DTT 16

typedef __attribute__((ext_vector_type(8))) short bf16x8;
typedef __attribute__((ext_vector_type(4))) float f32x4;
typedef const void __attribute__((address_space(1))) gv_t;
typedef void __attribute__((address_space(3))) lv_t;

__device__ __forceinline__ unsigned short f2bf(float x) {
    unsigned u = __float_as_uint(x);
    unsigned r = u + 0x7FFFu + ((u >> 16) & 1u);
    return (unsigned short)(r >> 16);
}
__device__ __forceinline__ float bf2f(unsigned short h) {
    return __uint_as_float((unsigned)h << 16);
}

// fast silu: x * rcp(1+exp(-x))  (v_rcp_f32, ~1e-7 rel err)
__device__ __forceinline__ float fsilu(float x) {
    return x * __builtin_amdgcn_rcpf(1.f + __expf(-x));
}

// DPP butterfly add within 16-lane rows (no LDS pipe, no lgkmcnt)
template<int CTRL>
__device__ __forceinline__ float dppadd(float x) {
    return x + __int_as_float(__builtin_amdgcn_mov_dpp(
        __float_as_int(x), CTRL, 0xf, 0xf, true));
}

// ---------------- conversion kernels ----------------
__global__ __launch_bounds__(256) void cvt_hilo(
    const float* __restrict__ in, unsigned short* __restrict__ hi,
    unsigned short* __restrict__ lo, int n4)
{
    int i = blockIdx.x * 256 + threadIdx.x;
    if (i >= n4) return;
    float4 x = ((const float4*)in)[i];
    ushort4 h, l;
    h.x = f2bf(x.x); l.x = f2bf(x.x - bf2f(h.x));
    h.y = f2bf(x.y); l.y = f2bf(x.y - bf2f(h.y));
    h.z = f2bf(x.z); l.z = f2bf(x.z - bf2f(h.z));
    h.w = f2bf(x.w); l.w = f2bf(x.w - bf2f(h.w));
    ((ushort4*)hi)[i] = h;
    ((ushort4*)lo)[i] = l;
}

// W: K x N row-major f32  ->  T: N x K row-major bf16 hi/lo
__global__ __launch_bounds__(256) void tcvt(
    const float* __restrict__ W, unsigned short* __restrict__ Thi,
    unsigned short* __restrict__ Tlo, int K, int N)
{
    __shared__ float t[32][33];
    int tx = threadIdx.x & 31, ty = threadIdx.x >> 5;
    int k0 = blockIdx.y * 32, n0 = blockIdx.x * 32;
    #pragma unroll
    for (int i = 0; i < 32; i += 8)
        t[ty + i][tx] = W[(size_t)(k0 + ty + i) * N + n0 + tx];
    __syncthreads();
    #pragma unroll
    for (int i = 0; i < 32; i += 8) {
        float v = t[tx][ty + i];
        size_t o = (size_t)(n0 + ty + i) * K + k0 + tx;
        unsigned short h = f2bf(v);
        Thi[o] = h;
        Tlo[o] = f2bf(v - bf2f(h));
    }
}

// pack dbc dt-rank cols (0..127, lda=160) -> dense bf16 hi/lo 8192x128
__global__ __launch_bounds__(256) void pack_dbc128(
    const float* __restrict__ dbc, unsigned short* __restrict__ hi,
    unsigned short* __restrict__ lo)
{
    int i = blockIdx.x * 256 + threadIdx.x;   // 0 .. 8192*32-1
    int r = i >> 5, c4 = (i & 31) << 2;
    float4 x = *(const float4*)&dbc[(size_t)r * 160 + c4];
    ushort4 h, l;
    h.x = f2bf(x.x); l.x = f2bf(x.x - bf2f(h.x));
    h.y = f2bf(x.y); l.y = f2bf(x.y - bf2f(h.y));
    h.z = f2bf(x.z); l.z = f2bf(x.z - bf2f(h.z));
    h.w = f2bf(x.w); l.w = f2bf(x.w - bf2f(h.w));
    size_t o = ((size_t)r * 128 + c4) >> 2;
    ((ushort4*)hi)[o] = h;
    ((ushort4*)lo)[o] = l;
}

// y' in xz x-cols (row stride 8192), gate with silu(z) from z-cols; pack bf16 hi/lo 8192x4096
__global__ __launch_bounds__(256) void ycvt(
    const float* __restrict__ xz, unsigned short* __restrict__ hi,
    unsigned short* __restrict__ lo)
{
    int i = blockIdx.x * 256 + threadIdx.x;   // 0 .. 8192*1024-1
    int r = i >> 10, c4 = (i & 1023) << 2;
    float4 x = *(const float4*)&xz[(size_t)r * 8192 + c4];
    float4 z = *(const float4*)&xz[(size_t)r * 8192 + DINNER + c4];
    x.x *= fsilu(z.x); x.y *= fsilu(z.y);
    x.z *= fsilu(z.z); x.w *= fsilu(z.w);
    ushort4 h, l;
    h.x = f2bf(x.x); l.x = f2bf(x.x - bf2f(h.x));
    h.y = f2bf(x.y); l.y = f2bf(x.y - bf2f(h.y));
    h.z = f2bf(x.z); l.z = f2bf(x.z - bf2f(h.z));
    h.w = f2bf(x.w); l.w = f2bf(x.w - bf2f(h.w));
    size_t o = ((size_t)r * 4096 + c4) >> 2;
    ((ushort4*)hi)[o] = h;
    ((ushort4*)lo)[o] = l;
}

// ---------------- MFMA split GEMM ----------------
// C(MxN,f32) = (Ahi+Alo)(Bhi) + Ahi*Blo;  A: MxK row-major bf16, B given as B^T: NxK row-major bf16
// LDS bank-swizzle (both-sides, rule #21): the 16B chunk index within each row's
// 64B k-block is XOR'd with ((row>>1)&3) -- applied on the GLOBAL source address
// (global_load_lds writes LDS linearly) and on the fragment ds_read offset.
// Raster: GROUP_M=8 grouped column-major -- consecutive linear block ids (which
// round-robin across XCDs) cover 8 A row-panels x the SAME B column-panel, so
// each XCD keeps its A panel L2-resident while B streams once through L3.
__device__ __forceinline__ void gload16(const unsigned short* g, unsigned short* l) {
    __builtin_amdgcn_global_load_lds((gv_t*)g, (lv_t*)l, 16, 0, 0);
}

__global__ __launch_bounds__(256) void gemm_mfma3(
    const unsigned short* __restrict__ Ahi, const unsigned short* __restrict__ Alo,
    const unsigned short* __restrict__ Bhi, const unsigned short* __restrict__ Blo,
    const float* __restrict__ bias, float* __restrict__ C,
    unsigned short* __restrict__ Chi, unsigned short* __restrict__ Clo,
    int M, int N, int K, int flags)
{
    __shared__ unsigned short sAh[128*32], sAl[128*32], sBh[128*32], sBl[128*32];
    int tid = threadIdx.x;
    int lane = tid & 63, wv = tid >> 6;
    int wm = wv >> 1, wn = wv & 1;

    // GROUP_M=8 grouped raster (nby = M/128 is always a multiple of 8 here)
    int nbx = gridDim.x;
    int lin = blockIdx.y * nbx + blockIdx.x;
    int gsz = nbx << 3;
    int grp = lin / gsz;
    int idx = lin - grp * gsz;
    int bm = ((grp << 3) + (idx & 7)) * 128;
    int bn = (idx >> 3) * 128;

    int rbase = wv * 32;
    int srow = lane >> 2;
    int scol = (((lane & 3) ^ ((srow >> 1) & 3)) << 3);   // swizzled source chunk
    const size_t aoff0 = (size_t)(bm + rbase + srow) * K + scol;
    const size_t aoff1 = aoff0 + (size_t)16 * K;
    const size_t boff0 = (size_t)(bn + rbase + srow) * K + scol;
    const size_t boff1 = boff0 + (size_t)16 * K;
    unsigned short* lA0 = &sAh[rbase * 32];
    unsigned short* lA1 = &sAh[(rbase + 16) * 32];
    unsigned short* lAl0 = &sAl[rbase * 32];
    unsigned short* lAl1 = &sAl[(rbase + 16) * 32];
    unsigned short* lB0 = &sBh[rbase * 32];
    unsigned short* lB1 = &sBh[(rbase + 16) * 32];
    unsigned short* lBl0 = &sBl[rbase * 32];
    unsigned short* lBl1 = &sBl[(rbase + 16) * 32];

    f32x4 acc[4][4];
    #pragma unroll
    for (int i = 0; i < 4; i++)
        #pragma unroll
        for (int j = 0; j < 4; j++)
            acc[i][j] = (f32x4){0.f, 0.f, 0.f, 0.f};

    int fr = lane & 15;
    int q8 = (((lane >> 4) ^ ((fr >> 1) & 3)) << 3);      // swizzled read chunk

    for (int k0 = 0; k0 < K; k0 += 32) {
        gload16(Ahi + aoff0 + k0, lA0);
        gload16(Ahi + aoff1 + k0, lA1);
        gload16(Alo + aoff0 + k0, lAl0);
        gload16(Alo + aoff1 + k0, lAl1);
        gload16(Bhi + boff0 + k0, lB0);
        gload16(Bhi + boff1 + k0, lB1);
        gload16(Blo + boff0 + k0, lBl0);
        gload16(Blo + boff1 + k0, lBl1);
        __syncthreads();

        bf16x8 ah[4], al[4], bh[4], bl[4];
        #pragma unroll
        for (int t = 0; t < 4; t++) {
            ah[t] = *(const bf16x8*)&sAh[(wm * 64 + t * 16 + fr) * 32 + q8];
            al[t] = *(const bf16x8*)&sAl[(wm * 64 + t * 16 + fr) * 32 + q8];
            bh[t] = *(const bf16x8*)&sBh[(wn * 64 + t * 16 + fr) * 32 + q8];
            bl[t] = *(const bf16x8*)&sBl[(wn * 64 + t * 16 + fr) * 32 + q8];
        }
        #pragma unroll
        for (int i = 0; i < 4; i++)
            #pragma unroll
            for (int j = 0; j < 4; j++) {
                acc[i][j] = __builtin_amdgcn_mfma_f32_16x16x32_bf16(ah[i], bh[j], acc[i][j], 0, 0, 0);
                acc[i][j] = __builtin_amdgcn_mfma_f32_16x16x32_bf16(al[i], bh[j], acc[i][j], 0, 0, 0);
                acc[i][j] = __builtin_amdgcn_mfma_f32_16x16x32_bf16(ah[i], bl[j], acc[i][j], 0, 0, 0);
            }
        __syncthreads();
    }

    // epilogue: C/D layout col=lane&15, row=(lane>>4)*4+reg
    int q4 = (lane >> 4) * 4, c16 = lane & 15;
    #pragma unroll
    for (int i = 0; i < 4; i++)
        #pragma unroll
        for (int j = 0; j < 4; j++) {
            f32x4 v = acc[i][j];
            int col = bn + wn * 64 + j * 16 + c16;
            float bv = (flags & FLAG_BIAS) ? bias[col] : 0.f;
            #pragma unroll
            for (int r = 0; r < 4; r++) {
                int row = bm + wm * 64 + i * 16 + q4 + r;
                float val = v[r] + bv;
                if (flags & FLAG_DTT) {
                    // softplus, write transposed f32 [b][d][t]
                    float sp = (val > 20.f) ? val : log1pf(__expf(val));
                    C[((size_t)(row >> 10) * 4096 + col) * 1024 + (row & 1023)] = sp;
                } else if (flags & FLAG_BF16) {
                    size_t o;
                    if (flags & FLAG_KT) {
                        int bi = row >> 10, jj = row & 1023;
                        int hd = col >> 8, dk2 = col & 255;
                        o = ((size_t)((bi * NH + hd) * DKH + dk2)) * SEQ + jj;
                    } else {
                        o = (size_t)row * N + col;
                    }
                    unsigned short hv = f2bf(val);
                    Chi[o] = hv;
                    Clo[o] = f2bf(val - bf2f(hv));
                } else if (flags & FLAG_KT) {
                    int bi = row >> 10, jj = row & 1023;
                    int hd = col >> 8, dk2 = col & 255;
                    C[((size_t)((bi * NH + hd) * DKH + dk2)) * SEQ + jj] = val;
                } else {
                    C[(size_t)row * N + col] = val;
                }
            }
        }
}

// ---------------- batched split GEMM for attention ----------------
__global__ __launch_bounds__(256) void gemm_att3(
    const unsigned short* __restrict__ Ahi, const unsigned short* __restrict__ Alo,
    const unsigned short* __restrict__ Bhi, const unsigned short* __restrict__ Blo,
    float* __restrict__ Cf, unsigned short* __restrict__ Ohi, unsigned short* __restrict__ Olo,
    int K, int lda, int ldb, int chunk_base, int mode)
{
    __shared__ unsigned short sAh[128*32], sAl[128*32], sBh[128*32], sBl[128*32];
    int tid = threadIdx.x;
    int lane = tid & 63, wv = tid >> 6;
    int wm = wv >> 1, wn = wv & 1;
    int bm = blockIdx.y * 128, bn = blockIdx.x * 128;
    int z = blockIdx.z;
    int g = chunk_base + z;

    size_t abase, bbase;
    if (mode == 0) {
        abase = (size_t)(g >> 3) * (1024 * 2048) + (size_t)(g & 7) * 256;
        bbase = abase;
    } else {
        abase = (size_t)z * (1024 * 2048);
        bbase = (size_t)g * (256 * 1024);
    }

    int rbase = wv * 32;
    int srow = lane >> 2;
    int scol = (((lane & 3) ^ ((srow >> 1) & 3)) << 3);   // swizzled source chunk
    const size_t aoff0 = abase + (size_t)(bm + rbase + srow) * lda + scol;
    const size_t aoff1 = aoff0 + (size_t)16 * lda;
    const size_t boff0 = bbase + (size_t)(bn + rbase + srow) * ldb + scol;
    const size_t boff1 = boff0 + (size_t)16 * ldb;
    unsigned short* lA0 = &sAh[rbase * 32];
    unsigned short* lA1 = &sAh[(rbase + 16) * 32];
    unsigned short* lAl0 = &sAl[rbase * 32];
    unsigned short* lAl1 = &sAl[(rbase + 16) * 32];
    unsigned short* lB0 = &sBh[rbase * 32];
    unsigned short* lB1 = &sBh[(rbase + 16) * 32];
    unsigned short* lBl0 = &sBl[rbase * 32];
    unsigned short* lBl1 = &sBl[(rbase + 16) * 32];

    f32x4 acc[4][4];
    #pragma unroll
    for (int i = 0; i < 4; i++)
        #pragma unroll
        for (int j = 0; j < 4; j++)
            acc[i][j] = (f32x4){0.f, 0.f, 0.f, 0.f};

    int fr = lane & 15;
    int q8 = (((lane >> 4) ^ ((fr >> 1) & 3)) << 3);      // swizzled read chunk

    for (int k0 = 0; k0 < K; k0 += 32) {
        gload16(Ahi + aoff0 + k0, lA0);
        gload16(Ahi + aoff1 + k0, lA1);
        gload16(Alo + aoff0 + k0, lAl0);
        gload16(Alo + aoff1 + k0, lAl1);
        gload16(Bhi + boff0 + k0, lB0);
        gload16(Bhi + boff1 + k0, lB1);
        gload16(Blo + boff0 + k0, lBl0);
        gload16(Blo + boff1 + k0, lBl1);
        __syncthreads();

        bf16x8 ah[4], al[4], bh[4], bl[4];
        #pragma unroll
        for (int t = 0; t < 4; t++) {
            ah[t] = *(const bf16x8*)&sAh[(wm * 64 + t * 16 + fr) * 32 + q8];
            al[t] = *(const bf16x8*)&sAl[(wm * 64 + t * 16 + fr) * 32 + q8];
            bh[t] = *(const bf16x8*)&sBh[(wn * 64 + t * 16 + fr) * 32 + q8];
            bl[t] = *(const bf16x8*)&sBl[(wn * 64 + t * 16 + fr) * 32 + q8];
        }
        #pragma unroll
        for (int i = 0; i < 4; i++)
            #pragma unroll
            for (int j = 0; j < 4; j++) {
                acc[i][j] = __builtin_amdgcn_mfma_f32_16x16x32_bf16(ah[i], bh[j], acc[i][j], 0, 0, 0);
                acc[i][j] = __builtin_amdgcn_mfma_f32_16x16x32_bf16(al[i], bh[j], acc[i][j], 0, 0, 0);
                acc[i][j] = __builtin_amdgcn_mfma_f32_16x16x32_bf16(ah[i], bl[j], acc[i][j], 0, 0, 0);
            }
        __syncthreads();
    }

    int q4 = (lane >> 4) * 4, c16 = lane & 15;
    #pragma unroll
    for (int i = 0; i < 4; i++)
        #pragma unroll
        for (int j = 0; j < 4; j++) {
            f32x4 v = acc[i][j];
            int col = bn + wn * 64 + j * 16 + c16;
            #pragma unroll
            for (int r = 0; r < 4; r++) {
                int row = bm + wm * 64 + i * 16 + q4 + r;
                float val = v[r];
                if (mode == 0) {
                    Cf[(size_t)z * (1024 * 1024) + (size_t)row * 1024 + col] = val * 0.0625f;
                } else {
                    size_t o = ((size_t)((g >> 3) * 1024 + row)) * 2048 + (size_t)(g & 7) * 256 + col;
                    unsigned short hv = f2bf(val);
                    Ohi[o] = hv;
                    Olo[o] = f2bf(val - bf2f(hv));
                }
            }
        }
}

// ---------------- row softmax, in-place f32 -> bf16 hi/lo ----------------
__global__ __launch_bounds__(256) void softmax_rows(float* __restrict__ S)
{
    int lane = threadIdx.x & 63, wid = threadIdx.x >> 6;
    size_t row = (size_t)blockIdx.x * 4 + wid;
    float* rp = S + row * 1024;

    float4 x[4];
    float m = -1e30f;
    #pragma unroll
    for (int w = 0; w < 4; w++) {
        x[w] = *(const float4*)&rp[w * 256 + lane * 4];
        m = fmaxf(m, fmaxf(fmaxf(x[w].x, x[w].y), fmaxf(x[w].z, x[w].w)));
    }
    #pragma unroll
    for (int off = 1; off < 64; off <<= 1) m = fmaxf(m, __shfl_xor(m, off));

    float s = 0.f;
    #pragma unroll
    for (int w = 0; w < 4; w++) {
        x[w].x = __expf(x[w].x - m);
        x[w].y = __expf(x[w].y - m);
        x[w].z = __expf(x[w].z - m);
        x[w].w = __expf(x[w].w - m);
        s += x[w].x + x[w].y + x[w].z + x[w].w;
    }
    #pragma unroll
    for (int off = 1; off < 64; off <<= 1) s += __shfl_xor(s, off);
    float inv = 1.f / s;

    unsigned short* hp = (unsigned short*)rp;
    unsigned short* lp = hp + 1024;
    #pragma unroll
    for (int w = 0; w < 4; w++) {
        float a0 = x[w].x * inv, a1 = x[w].y * inv;
        float a2 = x[w].z * inv, a3 = x[w].w * inv;
        ushort4 h, l;
        h.x = f2bf(a0); l.x = f2bf(a0 - bf2f(h.x));
        h.y = f2bf(a1); l.y = f2bf(a1 - bf2f(h.y));
        h.z = f2bf(a2); l.z = f2bf(a2 - bf2f(h.z));
        h.w = f2bf(a3); l.w = f2bf(a3 - bf2f(h.w));
        int c = w * 256 + lane * 4;
        *(ushort4*)&hp[c] = h;
        *(ushort4*)&lp[c] = l;
    }
}

// ---------------- fp32 GEMM (small shapes) ----------------
#define BM 64
#define BN 64
#define BK 16
__global__ __launch_bounds__(256) void gemm_f32(
    const float* __restrict__ A, const float* __restrict__ B,
    const float* __restrict__ bias, float* __restrict__ C,
    int M, int N, int K, int lda, int ldb, int ldc, int flags)
{
    __shared__ float As[BK][BM + 4];
    __shared__ float Bs[BK][BN + 4];
    int tid = threadIdx.x;
    int tm = tid >> 4, tn = tid & 15;
    int bm = blockIdx.y * BM, bn = blockIdx.x * BN;
    float acc[4][4] = {};

    for (int k0 = 0; k0 < K; k0 += BK) {
        #pragma unroll
        for (int i = 0; i < 4; i++) {
            int idx = tid + i * 256;
            int r = idx >> 4, c = idx & 15;
            int gr = bm + r, gc = k0 + c;
            float v = 0.f;
            if (gr < M && gc < K) v = A[(size_t)gr * lda + gc];
            As[c][r] = v;
        }
        #pragma unroll
        for (int i = 0; i < 4; i++) {
            int idx = tid + i * 256;
            int r = idx >> 6, c = idx & 63;
            int gr = k0 + r, gc = bn + c;
            float v = 0.f;
            if (gr < K && gc < N) v = B[(size_t)gr * ldb + gc];
            Bs[r][c] = v;
        }
        __syncthreads();
        #pragma unroll
        for (int kk = 0; kk < BK; kk++) {
            float4 a4 = *(const float4*)&As[kk][tm * 4];
            float4 b4 = *(const float4*)&Bs[kk][tn * 4];
            float av[4] = {a4.x, a4.y, a4.z, a4.w};
            float bv[4] = {b4.x, b4.y, b4.z, b4.w};
            #pragma unroll
            for (int i = 0; i < 4; i++)
                #pragma unroll
                for (int j = 0; j < 4; j++)
                    acc[i][j] += av[i] * bv[j];
        }
        __syncthreads();
    }

    #pragma unroll
    for (int i = 0; i < 4; i++) {
        int row = bm + tm * 4 + i;
        if (row >= M) continue;
        #pragma unroll
        for (int j = 0; j < 4; j++) {
            int col = bn + tn * 4 + j;
            if (col >= N) continue;
            float val = acc[i][j];
            if (flags & FLAG_BIAS) val += bias[col];
            if (flags & FLAG_SOFTPLUS) val = (val > 20.f) ? val : log1pf(__expf(val));
            C[(size_t)row * ldc + col] = val;
        }
    }
}

// ---------------- BC repack: dbc[row][128+n],[144+n] -> interleaved pairs at cols 0..31 ----------------
__global__ __launch_bounds__(256) void repack_bc(float* __restrict__ dbc)
{
    int i = blockIdx.x * 256 + threadIdx.x;   // 0 .. 8192*16-1
    int n = i & 15;
    int row = i >> 4;
    float B = dbc[(size_t)row * 160 + DTRANK + n];
    float C = dbc[(size_t)row * 160 + DTRANK + DSTATE + n];
    float2 p; p.x = B; p.y = C;
    ((float2*)&dbc[(size_t)row * 160])[n] = p;
}

// ---------------- conv+silu transpose: x[t][d] -> xsT[b][d][t] ----------------
// grid (64 d-tiles, 128 t-tiles), 256 threads, 64x64 tile
__global__ __launch_bounds__(256) void conv_prep(
    const float* __restrict__ xz, float* __restrict__ xsT,
    const float* __restrict__ conv_w, const float* __restrict__ conv_b)
{
    __shared__ float sx[67][68];
    int tid = threadIdx.x;
    int d0 = blockIdx.x * 64;
    int t0 = blockIdx.y * 64;           // global row index (b*1024 + tloc)
    int tloc0 = t0 & 1023;

    // load rows t0-3 .. t0+63 (67 rows x 64 d), zero halo at sequence start
    int lr = tid >> 2;                  // 0..63
    int lc = (tid & 3) * 16;            // 0,16,32,48
    for (int rr = lr; rr < 67; rr += 64) {
        int tg = t0 - 3 + rr;
        bool ok = (tloc0 != 0) || (rr >= 3);
        #pragma unroll
        for (int c = 0; c < 16; c += 4) {
            float4 v = ok ? *(const float4*)&xz[(size_t)tg * 8192 + d0 + lc + c]
                          : (float4){0.f, 0.f, 0.f, 0.f};
            *(float4*)&sx[rr][lc + c] = v;
        }
    }
    __syncthreads();

    // compute: thread -> d = d0 + (tid>>2), t quarter = (tid&3)*16
    int dr = tid >> 2;
    int tq = (tid & 3) * 16;
    int d = d0 + dr;
    float cw0 = conv_w[d * 4 + 0], cw1 = conv_w[d * 4 + 1];
    float cw2 = conv_w[d * 4 + 2], cw3 = conv_w[d * 4 + 3];
    float cb = conv_b[d];

    float x0 = sx[tq + 0][dr], x1 = sx[tq + 1][dr], x2 = sx[tq + 2][dr];
    float o[16];
    #pragma unroll
    for (int tt = 0; tt < 16; tt++) {
        float x3 = sx[tq + tt + 3][dr];
        float xc = cw0 * x0 + cw1 * x1 + cw2 * x2 + cw3 * x3 + cb;
        o[tt] = fsilu(xc);
        x0 = x1; x1 = x2; x2 = x3;
    }
    size_t ob = ((size_t)(t0 >> 10) * 4096 + d) * 1024 + tloc0 + tq;
    #pragma unroll
    for (int c = 0; c < 16; c += 4)
        *(float4*)&xsT[ob + c] = (float4){o[c], o[c+1], o[c+2], o[c+3]};
}

// ---------------- lean mamba scan (transposed streams, LDS chunked) ----------------
// xsT/dtT: f32 [8][4096][1024]; bc: packed (B,C) pairs at dbc cols 0..31.
// writes y' = p + dsk*xs (pre-gate) into xz x-cols [t][d].
__global__ __launch_bounds__(256) void mamba_scan(
    float* __restrict__ xz, const float* __restrict__ dtT,
    const float* __restrict__ bc, const float* __restrict__ A_log,
    const float* __restrict__ D_skip, const float* __restrict__ xsT)
{
    __shared__ float sxs[16 * 68];
    __shared__ float sdt[16 * 68];
    __shared__ float sbc[64 * 32];

    int tid = threadIdx.x;
    int n = tid & 15;
    int dd = tid >> 4;
    int gb = blockIdx.x;
    int b = gb >> 8;
    int d0 = (gb & 255) << 4;
    int d = d0 + dd;

    float A_n = -__expf(A_log[d * DSTATE + n]);
    float dsk = D_skip[d];
    float h = 0.f;

    size_t baseT = ((size_t)b * 4096 + d0) * 1024;
    size_t rowbc = (size_t)b * SEQ * 160;
    size_t rowx  = (size_t)b * SEQ * 8192 + d;

    int sr = tid >> 4;            // 0..15: d-row for xs/dt staging
    int sc = (tid & 15) * 4;      // float4 col
    int br = tid >> 2;            // 0..63: t-row for bc staging
    int bq = (tid & 3) * 8;

    for (int t0 = 0; t0 < SEQ; t0 += 64) {
        float4 vx = *(const float4*)&xsT[baseT + (size_t)sr * 1024 + t0 + sc];
        float4 vd = *(const float4*)&dtT[baseT + (size_t)sr * 1024 + t0 + sc];
        float4 v0 = *(const float4*)&bc[rowbc + (size_t)(t0 + br) * 160 + bq];
        float4 v1 = *(const float4*)&bc[rowbc + (size_t)(t0 + br) * 160 + bq + 4];
        __syncthreads();
        *(float4*)&sxs[sr * 68 + sc] = vx;
        *(float4*)&sdt[sr * 68 + sc] = vd;
        *(float4*)&sbc[br * 32 + bq] = v0;
        *(float4*)&sbc[br * 32 + bq + 4] = v1;
        __syncthreads();

        #pragma unroll 4
        for (int tl = 0; tl < 64; tl++) {
            float xv  = sxs[dd * 68 + tl];
            float dtv = sdt[dd * 68 + tl];
            float2 bcv = *(const float2*)&sbc[tl * 32 + 2 * n];
            float dA = __expf(dtv * A_n);
            h = dA * h + (dtv * xv) * bcv.x;
            float p = h * bcv.y;
            p = dppadd<0xB1>(p);    // quad_perm xor1
            p = dppadd<0x4E>(p);    // quad_perm xor2
            p = dppadd<0x141>(p);   // row_half_mirror
            p = dppadd<0x140>(p);   // row_mirror
            if (n == 0)
                xz[rowx + (size_t)(t0 + tl) * 8192] = p + dsk * xv;
        }
    }
}

// ---------------- launcher ----------------
extern "C" void kernel_launch(void* const* d_in, const int* in_sizes, int n_in,
                              void* d_out, int out_size, void* d_ws, size_t ws_size,
                              hipStream_t stream) {
    const float* imgF   = (const float*)d_in[0];
    const float* kf     = (const float*)d_in[1];
    const float* Wq     = (const float*)d_in[2];
    const float* bq     = (const float*)d_in[3];
    const float* Wk     = (const float*)d_in[4];
    const float* bk     = (const float*)d_in[5];
    const float* Wv     = (const float*)d_in[6];
    const float* bv     = (const float*)d_in[7];
    const float* Wo     = (const float*)d_in[8];
    const float* bo     = (const float*)d_in[9];
    const float* W_in   = (const float*)d_in[10];
    const float* conv_w = (const float*)d_in[11];
    const float* conv_b = (const float*)d_in[12];
    const float* W_extra= (const float*)d_in[13];
    const float* W_xproj= (const float*)d_in[14];
    const float* W_dt   = (const float*)d_in[15];
    const float* b_dt   = (const float*)d_in[16];
    const float* A_log  = (const float*)d_in[17];
    const float* D_skip = (const float*)d_in[18];
    const float* W_out  = (const float*)d_in[19];
    float* out = (float*)d_out;
    char* W = (char*)d_ws;

    #define WS_F(off) ((float*)(W + (off)))
    #define WS_U(off) ((unsigned short*)(W + (off)))

    dim3 blk(256);
    auto gg = [](int M, int N) { return dim3((N + BN - 1) / BN, (M + BM - 1) / BM); };

    // ===== mamba phase =====
    // imgF -> bf16 hi/lo
    cvt_hilo<<<dim3(16384), blk, 0, stream>>>(imgF, WS_U(O_IMGH), WS_U(O_IMGL), 4194304);
    // W_in (2048x8192) -> W_in^T hi/lo
    tcvt<<<dim3(8192/32, 2048/32), blk, 0, stream>>>(W_in, WS_U(O_WINTH), WS_U(O_WINTL), 2048, 8192);
    // xz = imgF @ W_in   (M=8192, N=8192, K=2048)
    gemm_mfma3<<<dim3(64, 64), blk, 0, stream>>>(WS_U(O_IMGH), WS_U(O_IMGL),
        WS_U(O_WINTH), WS_U(O_WINTL), nullptr, WS_F(O_XZ), nullptr, nullptr,
        8192, 8192, 2048, 0);
    // Wcomb = W_extra @ W_xproj   (2048x160, K=4096)
    gemm_f32<<<gg(2048, 160), blk, 0, stream>>>(W_extra, W_xproj, nullptr, WS_F(O_WCOMB),
        2048, 160, 4096, 4096, 160, 160, 0);
    // dbc = kf @ Wcomb
    gemm_f32<<<gg(8192, 160), blk, 0, stream>>>(kf, WS_F(O_WCOMB), nullptr, WS_F(O_DBC),
        8192, 160, 2048, 2048, 160, 160, 0);
    // pack dbc dt-rank cols -> bf16 hi/lo (imgh region is dead now)
    pack_dbc128<<<dim3(1024), blk, 0, stream>>>(WS_F(O_DBC), WS_U(O_DBCH), WS_U(O_DBCL));
    // pack (B,C) pairs into dead dt-rank cols of dbc
    repack_bc<<<dim3(512), blk, 0, stream>>>(WS_F(O_DBC));
    // W_dt (128x4096) -> W_dt^T hi/lo
    tcvt<<<dim3(4096/32, 128/32), blk, 0, stream>>>(W_dt, WS_U(O_WDTH), WS_U(O_WDTL), 128, 4096);
    // dtT = softplus(dbc128 @ W_dt + b_dt) transposed [b][d][t] -> d_out
    gemm_mfma3<<<dim3(32, 64), blk, 0, stream>>>(WS_U(O_DBCH), WS_U(O_DBCL),
        WS_U(O_WDTH), WS_U(O_WDTL), b_dt, out, nullptr, nullptr,
        8192, 4096, 128, FLAG_BIAS | FLAG_DTT);
    // xsT = silu(conv(x)) transposed [b][d][t]  (clobbers dbc128/wdt copies - dead)
    conv_prep<<<dim3(64, 128), blk, 0, stream>>>(WS_F(O_XZ), WS_F(O_XST), conv_w, conv_b);
    // lean scan: y' -> xz x-cols
    mamba_scan<<<dim3(2048), blk, 0, stream>>>(WS_F(O_XZ), out, WS_F(O_DBC),
        A_log, D_skip, WS_F(O_XST));
    // y = y' * silu(z) -> bf16 hi/lo (over xsT - dead)
    ycvt<<<dim3(32768), blk, 0, stream>>>(WS_F(O_XZ), WS_U(O_YH), WS_U(O_YL));
    // W_out (4096x2048) -> W_out^T hi/lo (xz dead)
    tcvt<<<dim3(2048/32, 4096/32), blk, 0, stream>>>(W_out, WS_U(O_WOUTH), WS_U(O_WOUTL), 4096, 2048);
    // out1 = y @ W_out   (M=8192, N=2048, K=4096)  (dtT in d_out dead)
    gemm_mfma3<<<dim3(16, 64), blk, 0, stream>>>(WS_U(O_YH), WS_U(O_YL),
        WS_U(O_WOUTH), WS_U(O_WOUTL), nullptr, out + 16777216, nullptr, nullptr,
        8192, 2048, 4096, 0);

    // ===== attention phase =====
    cvt_hilo<<<dim3(16384), blk, 0, stream>>>(imgF, WS_U(A_IMGH), WS_U(A_IMGL), 4194304);
    tcvt<<<dim3(64, 64), blk, 0, stream>>>(Wq, WS_U(A_WQH), WS_U(A_WQL), 2048, 2048);
    tcvt<<<dim3(64, 64), blk, 0, stream>>>(Wk, WS_U(A_WKH), WS_U(A_WKL), 2048, 2048);
    tcvt<<<dim3(64, 64), blk, 0, stream>>>(Wv, WS_U(A_WVH), WS_U(A_WVL), 2048, 2048);
    tcvt<<<dim3(64, 64), blk, 0, stream>>>(Wo, WS_U(A_WOH), WS_U(A_WOL), 2048, 2048);
    // q = imgF @ Wq + bq  -> bf16 hi/lo 8192x2048
    gemm_mfma3<<<dim3(16, 64), blk, 0, stream>>>(WS_U(A_IMGH), WS_U(A_IMGL),
        WS_U(A_WQH), WS_U(A_WQL), bq, nullptr, WS_U(A_QH), WS_U(A_QL),
        8192, 2048, 2048, FLAG_BIAS | FLAG_BF16);
    // k = imgF @ Wk + bk  -> bf16 hi/lo 8192x2048 (natural layout == B^T for S)
    gemm_mfma3<<<dim3(16, 64), blk, 0, stream>>>(WS_U(A_IMGH), WS_U(A_IMGL),
        WS_U(A_WKH), WS_U(A_WKL), bk, nullptr, WS_U(A_KH), WS_U(A_KL),
        8192, 2048, 2048, FLAG_BIAS | FLAG_BF16);
    // v^T = (imgF @ Wv + bv) transposed per (b,h) -> bf16 hi/lo (b,h,dk,seq)
    gemm_mfma3<<<dim3(16, 64), blk, 0, stream>>>(WS_U(A_IMGH), WS_U(A_IMGL),
        WS_U(A_WVH), WS_U(A_WVL), bv, nullptr, WS_U(A_VTH), WS_U(A_VTL),
        8192, 2048, 2048, FLAG_BIAS | FLAG_BF16 | FLAG_KT);
    // chunked attention: 4 chunks x 16 (b,h) batches, 64 MiB score buffer
    for (int c = 0; c < 4; c++) {
        gemm_att3<<<dim3(8, 8, 16), blk, 0, stream>>>(WS_U(A_QH), WS_U(A_QL),
            WS_U(A_KH), WS_U(A_KL), WS_F(A_S), nullptr, nullptr,
            256, 2048, 2048, c * 16, 0);
        softmax_rows<<<dim3(4096), blk, 0, stream>>>(WS_F(A_S));
        gemm_att3<<<dim3(2, 8, 16), blk, 0, stream>>>(
            (unsigned short*)WS_F(A_S), (unsigned short*)WS_F(A_S) + 1024,
            WS_U(A_VTH), WS_U(A_VTL), nullptr, WS_U(A_ATTH), WS_U(A_ATTL),
            1024, 2048, 1024, c * 16, 1);
    }
    // out0 = att @ Wo + bo
    gemm_mfma3<<<dim3(16, 64), blk, 0, stream>>>(WS_U(A_ATTH), WS_U(A_ATTL),
        WS_U(A_WOH), WS_U(A_WOL), bo, out, nullptr, nullptr,
        8192, 2048, 2048, FLAG_BIAS);
}

// Round 6
// 4656.498 us; speedup vs baseline: 1.0373x; 1.0331x over previous
//
#include <hip/hip_runtime.h>
#include <math.h>

#define NH 8
#define DKH 256
#define SEQ 1024
#define BSZ 8
#define DMODEL 2048
#define DINNER 4096
#define DSTATE 16
#define DTRANK 128

#define MiB 1048576ULL

// ---------------- workspace byte offsets ----------------
// mamba phase
#define O_XZ    (0*MiB)                  // f32 8192x8192 (x cols 0..4095, z 4096..8191)
#define O_IMGH  (256*MiB)                // bf16 8192x2048 imgF hi
#define O_IMGL  (288*MiB)
#define O_WINTH (320*MiB)                // bf16 8192x2048  W_in^T hi
#define O_WINTL (352*MiB)
#define O_WCOMB (384*MiB)                // f32 2048x160
#define O_DBC   (384*MiB + 1310720ULL)   // f32 8192x160   (ends exactly at 409206784)
// after xz GEMM, [256,384) is reused:
#define O_DBCH  (256*MiB)                // bf16 8192x128 (dbc dt-rank cols)
#define O_DBCL  (259*MiB)
#define O_WDTH  (262*MiB)                // bf16 4096x128 (W_dt^T)
#define O_WDTL  (264*MiB)
#define O_XST   (256*MiB)                // f32 [8][4096][1024] xs transposed (after dt GEMM)
#define O_YH    (256*MiB)                // bf16 8192x4096 (after ycvt, over xsT)
#define O_YL    (320*MiB)
#define O_WOUTH (0*MiB)                  // bf16 2048x4096 (after ycvt)
#define O_WOUTL (16*MiB)
// dtT f32 [8][4096][1024] lives in d_out (128 MiB), dead before out1 GEMM writes
// attention phase (after out1)
#define A_IMGH  (0*MiB)
#define A_IMGL  (32*MiB)
#define A_WQH   (64*MiB)
#define A_WQL   (72*MiB)
#define A_WKH   (80*MiB)
#define A_WKL   (88*MiB)
#define A_WVH   (96*MiB)
#define A_WVL   (104*MiB)
#define A_WOH   (112*MiB)
#define A_WOL   (120*MiB)
#define A_QH    (128*MiB)                // bf16 8192x2048
#define A_QL    (160*MiB)
#define A_KH    (192*MiB)                // bf16 8192x2048 (natural layout == B^T for QK^T)
#define A_KL    (224*MiB)
#define A_VTH   (256*MiB)                // bf16 (b,h,dk,seq) = 64x256x1024
#define A_VTL   (288*MiB)
#define A_S     (320*MiB)                // 64 MiB: 16 batches x 1024 x 1024 f32 (chunked)
#define A_ATTH  (0*MiB)                  // bf16 8192x2048 (img freed by then)
#define A_ATTL  (32*MiB)

#define FLAG_BIAS 1
#define FLAG_SOFTPLUS 2
#define FLAG_KT 4
#define FLAG_BF16 8
#define FLAG_DTT 16

typedef __attribute__((ext_vector_type(8))) short bf16x8;
typedef __attribute__((ext_vector_type(4))) float f32x4;
typedef const void __attribute__((address_space(1))) gv_t;
typedef void __attribute__((address_space(3))) lv_t;

__device__ __forceinline__ unsigned short f2bf(float x) {
    unsigned u = __float_as_uint(x);
    unsigned r = u + 0x7FFFu + ((u >> 16) & 1u);
    return (unsigned short)(r >> 16);
}
__device__ __forceinline__ float bf2f(unsigned short h) {
    return __uint_as_float((unsigned)h << 16);
}

// fast silu: x * rcp(1+exp(-x))  (v_rcp_f32, ~1e-7 rel err)
__device__ __forceinline__ float fsilu(float x) {
    return x * __builtin_amdgcn_rcpf(1.f + __expf(-x));
}

// DPP butterfly add within 16-lane rows (no LDS pipe, no lgkmcnt)
template<int CTRL>
__device__ __forceinline__ float dppadd(float x) {
    return x + __int_as_float(__builtin_amdgcn_mov_dpp(
        __float_as_int(x), CTRL, 0xf, 0xf, true));
}

// ---------------- conversion kernels ----------------
__global__ __launch_bounds__(256) void cvt_hilo(
    const float* __restrict__ in, unsigned short* __restrict__ hi,
    unsigned short* __restrict__ lo, int n4)
{
    int i = blockIdx.x * 256 + threadIdx.x;
    if (i >= n4) return;
    float4 x = ((const float4*)in)[i];
    ushort4 h, l;
    h.x = f2bf(x.x); l.x = f2bf(x.x - bf2f(h.x));
    h.y = f2bf(x.y); l.y = f2bf(x.y - bf2f(h.y));
    h.z = f2bf(x.z); l.z = f2bf(x.z - bf2f(h.z));
    h.w = f2bf(x.w); l.w = f2bf(x.w - bf2f(h.w));
    ((ushort4*)hi)[i] = h;
    ((ushort4*)lo)[i] = l;
}

// W: K x N row-major f32  ->  T: N x K row-major bf16 hi/lo
__global__ __launch_bounds__(256) void tcvt(
    const float* __restrict__ W, unsigned short* __restrict__ Thi,
    unsigned short* __restrict__ Tlo, int K, int N)
{
    __shared__ float t[32][33];
    int tx = threadIdx.x & 31, ty = threadIdx.x >> 5;
    int k0 = blockIdx.y * 32, n0 = blockIdx.x * 32;
    #pragma unroll
    for (int i = 0; i < 32; i += 8)
        t[ty + i][tx] = W[(size_t)(k0 + ty + i) * N + n0 + tx];
    __syncthreads();
    #pragma unroll
    for (int i = 0; i < 32; i += 8) {
        float v = t[tx][ty + i];
        size_t o = (size_t)(n0 + ty + i) * K + k0 + tx;
        unsigned short h = f2bf(v);
        Thi[o] = h;
        Tlo[o] = f2bf(v - bf2f(h));
    }
}

// pack dbc dt-rank cols (0..127, lda=160) -> dense bf16 hi/lo 8192x128
__global__ __launch_bounds__(256) void pack_dbc128(
    const float* __restrict__ dbc, unsigned short* __restrict__ hi,
    unsigned short* __restrict__ lo)
{
    int i = blockIdx.x * 256 + threadIdx.x;   // 0 .. 8192*32-1
    int r = i >> 5, c4 = (i & 31) << 2;
    float4 x = *(const float4*)&dbc[(size_t)r * 160 + c4];
    ushort4 h, l;
    h.x = f2bf(x.x); l.x = f2bf(x.x - bf2f(h.x));
    h.y = f2bf(x.y); l.y = f2bf(x.y - bf2f(h.y));
    h.z = f2bf(x.z); l.z = f2bf(x.z - bf2f(h.z));
    h.w = f2bf(x.w); l.w = f2bf(x.w - bf2f(h.w));
    size_t o = ((size_t)r * 128 + c4) >> 2;
    ((ushort4*)hi)[o] = h;
    ((ushort4*)lo)[o] = l;
}

// y' in xz x-cols (row stride 8192), gate with silu(z) from z-cols; pack bf16 hi/lo 8192x4096
__global__ __launch_bounds__(256) void ycvt(
    const float* __restrict__ xz, unsigned short* __restrict__ hi,
    unsigned short* __restrict__ lo)
{
    int i = blockIdx.x * 256 + threadIdx.x;   // 0 .. 8192*1024-1
    int r = i >> 10, c4 = (i & 1023) << 2;
    float4 x = *(const float4*)&xz[(size_t)r * 8192 + c4];
    float4 z = *(const float4*)&xz[(size_t)r * 8192 + DINNER + c4];
    x.x *= fsilu(z.x); x.y *= fsilu(z.y);
    x.z *= fsilu(z.z); x.w *= fsilu(z.w);
    ushort4 h, l;
    h.x = f2bf(x.x); l.x = f2bf(x.x - bf2f(h.x));
    h.y = f2bf(x.y); l.y = f2bf(x.y - bf2f(h.y));
    h.z = f2bf(x.z); l.z = f2bf(x.z - bf2f(h.z));
    h.w = f2bf(x.w); l.w = f2bf(x.w - bf2f(h.w));
    size_t o = ((size_t)r * 4096 + c4) >> 2;
    ((ushort4*)hi)[o] = h;
    ((ushort4*)lo)[o] = l;
}

// ---------------- MFMA split GEMM ----------------
// C(MxN,f32) = (Ahi+Alo)(Bhi) + Ahi*Blo;  A: MxK row-major bf16, B given as B^T: NxK row-major bf16
// LDS bank-swizzle (both-sides, rule #21): the 16B chunk index within each row's
// 64B k-block is XOR'd with ((row>>1)&3) -- applied on the GLOBAL source address
// (global_load_lds writes LDS linearly) and on the fragment ds_read offset.
// Raster: DEFAULT blockIdx raster. Measured (R3 vs R4/R5): custom XCD/grouped
// rasters doubled L2-miss FETCH (1.2->2.3 GB) and cost ~8%; default wins at
// these L3-fit working sets.
__device__ __forceinline__ void gload16(const unsigned short* g, unsigned short* l) {
    __builtin_amdgcn_global_load_lds((gv_t*)g, (lv_t*)l, 16, 0, 0);
}

__global__ __launch_bounds__(256) void gemm_mfma3(
    const unsigned short* __restrict__ Ahi, const unsigned short* __restrict__ Alo,
    const unsigned short* __restrict__ Bhi, const unsigned short* __restrict__ Blo,
    const float* __restrict__ bias, float* __restrict__ C,
    unsigned short* __restrict__ Chi, unsigned short* __restrict__ Clo,
    int M, int N, int K, int flags)
{
    __shared__ unsigned short sAh[128*32], sAl[128*32], sBh[128*32], sBl[128*32];
    int tid = threadIdx.x;
    int lane = tid & 63, wv = tid >> 6;
    int wm = wv >> 1, wn = wv & 1;
    int bm = blockIdx.y * 128, bn = blockIdx.x * 128;

    int rbase = wv * 32;
    int srow = lane >> 2;
    int scol = (((lane & 3) ^ ((srow >> 1) & 3)) << 3);   // swizzled source chunk
    const size_t aoff0 = (size_t)(bm + rbase + srow) * K + scol;
    const size_t aoff1 = aoff0 + (size_t)16 * K;
    const size_t boff0 = (size_t)(bn + rbase + srow) * K + scol;
    const size_t boff1 = boff0 + (size_t)16 * K;
    unsigned short* lA0 = &sAh[rbase * 32];
    unsigned short* lA1 = &sAh[(rbase + 16) * 32];
    unsigned short* lAl0 = &sAl[rbase * 32];
    unsigned short* lAl1 = &sAl[(rbase + 16) * 32];
    unsigned short* lB0 = &sBh[rbase * 32];
    unsigned short* lB1 = &sBh[(rbase + 16) * 32];
    unsigned short* lBl0 = &sBl[rbase * 32];
    unsigned short* lBl1 = &sBl[(rbase + 16) * 32];

    f32x4 acc[4][4];
    #pragma unroll
    for (int i = 0; i < 4; i++)
        #pragma unroll
        for (int j = 0; j < 4; j++)
            acc[i][j] = (f32x4){0.f, 0.f, 0.f, 0.f};

    int fr = lane & 15;
    int q8 = (((lane >> 4) ^ ((fr >> 1) & 3)) << 3);      // swizzled read chunk

    for (int k0 = 0; k0 < K; k0 += 32) {
        gload16(Ahi + aoff0 + k0, lA0);
        gload16(Ahi + aoff1 + k0, lA1);
        gload16(Alo + aoff0 + k0, lAl0);
        gload16(Alo + aoff1 + k0, lAl1);
        gload16(Bhi + boff0 + k0, lB0);
        gload16(Bhi + boff1 + k0, lB1);
        gload16(Blo + boff0 + k0, lBl0);
        gload16(Blo + boff1 + k0, lBl1);
        __syncthreads();

        bf16x8 ah[4], al[4], bh[4], bl[4];
        #pragma unroll
        for (int t = 0; t < 4; t++) {
            ah[t] = *(const bf16x8*)&sAh[(wm * 64 + t * 16 + fr) * 32 + q8];
            al[t] = *(const bf16x8*)&sAl[(wm * 64 + t * 16 + fr) * 32 + q8];
            bh[t] = *(const bf16x8*)&sBh[(wn * 64 + t * 16 + fr) * 32 + q8];
            bl[t] = *(const bf16x8*)&sBl[(wn * 64 + t * 16 + fr) * 32 + q8];
        }
        #pragma unroll
        for (int i = 0; i < 4; i++)
            #pragma unroll
            for (int j = 0; j < 4; j++) {
                acc[i][j] = __builtin_amdgcn_mfma_f32_16x16x32_bf16(ah[i], bh[j], acc[i][j], 0, 0, 0);
                acc[i][j] = __builtin_amdgcn_mfma_f32_16x16x32_bf16(al[i], bh[j], acc[i][j], 0, 0, 0);
                acc[i][j] = __builtin_amdgcn_mfma_f32_16x16x32_bf16(ah[i], bl[j], acc[i][j], 0, 0, 0);
            }
        __syncthreads();
    }

    // epilogue: C/D layout col=lane&15, row=(lane>>4)*4+reg
    int q4 = (lane >> 4) * 4, c16 = lane & 15;
    #pragma unroll
    for (int i = 0; i < 4; i++)
        #pragma unroll
        for (int j = 0; j < 4; j++) {
            f32x4 v = acc[i][j];
            int col = bn + wn * 64 + j * 16 + c16;
            float bv = (flags & FLAG_BIAS) ? bias[col] : 0.f;
            #pragma unroll
            for (int r = 0; r < 4; r++) {
                int row = bm + wm * 64 + i * 16 + q4 + r;
                float val = v[r] + bv;
                if (flags & FLAG_DTT) {
                    // softplus, write transposed f32 [b][d][t]
                    float sp = (val > 20.f) ? val : log1pf(__expf(val));
                    C[((size_t)(row >> 10) * 4096 + col) * 1024 + (row & 1023)] = sp;
                } else if (flags & FLAG_BF16) {
                    size_t o;
                    if (flags & FLAG_KT) {
                        int bi = row >> 10, jj = row & 1023;
                        int hd = col >> 8, dk2 = col & 255;
                        o = ((size_t)((bi * NH + hd) * DKH + dk2)) * SEQ + jj;
                    } else {
                        o = (size_t)row * N + col;
                    }
                    unsigned short hv = f2bf(val);
                    Chi[o] = hv;
                    Clo[o] = f2bf(val - bf2f(hv));
                } else if (flags & FLAG_KT) {
                    int bi = row >> 10, jj = row & 1023;
                    int hd = col >> 8, dk2 = col & 255;
                    C[((size_t)((bi * NH + hd) * DKH + dk2)) * SEQ + jj] = val;
                } else {
                    C[(size_t)row * N + col] = val;
                }
            }
        }
}

// ---------------- batched split GEMM for attention ----------------
__global__ __launch_bounds__(256) void gemm_att3(
    const unsigned short* __restrict__ Ahi, const unsigned short* __restrict__ Alo,
    const unsigned short* __restrict__ Bhi, const unsigned short* __restrict__ Blo,
    float* __restrict__ Cf, unsigned short* __restrict__ Ohi, unsigned short* __restrict__ Olo,
    int K, int lda, int ldb, int chunk_base, int mode)
{
    __shared__ unsigned short sAh[128*32], sAl[128*32], sBh[128*32], sBl[128*32];
    int tid = threadIdx.x;
    int lane = tid & 63, wv = tid >> 6;
    int wm = wv >> 1, wn = wv & 1;
    int bm = blockIdx.y * 128, bn = blockIdx.x * 128;
    int z = blockIdx.z;
    int g = chunk_base + z;

    size_t abase, bbase;
    if (mode == 0) {
        abase = (size_t)(g >> 3) * (1024 * 2048) + (size_t)(g & 7) * 256;
        bbase = abase;
    } else {
        abase = (size_t)z * (1024 * 2048);
        bbase = (size_t)g * (256 * 1024);
    }

    int rbase = wv * 32;
    int srow = lane >> 2;
    int scol = (((lane & 3) ^ ((srow >> 1) & 3)) << 3);   // swizzled source chunk
    const size_t aoff0 = abase + (size_t)(bm + rbase + srow) * lda + scol;
    const size_t aoff1 = aoff0 + (size_t)16 * lda;
    const size_t boff0 = bbase + (size_t)(bn + rbase + srow) * ldb + scol;
    const size_t boff1 = boff0 + (size_t)16 * ldb;
    unsigned short* lA0 = &sAh[rbase * 32];
    unsigned short* lA1 = &sAh[(rbase + 16) * 32];
    unsigned short* lAl0 = &sAl[rbase * 32];
    unsigned short* lAl1 = &sAl[(rbase + 16) * 32];
    unsigned short* lB0 = &sBh[rbase * 32];
    unsigned short* lB1 = &sBh[(rbase + 16) * 32];
    unsigned short* lBl0 = &sBl[rbase * 32];
    unsigned short* lBl1 = &sBl[(rbase + 16) * 32];

    f32x4 acc[4][4];
    #pragma unroll
    for (int i = 0; i < 4; i++)
        #pragma unroll
        for (int j = 0; j < 4; j++)
            acc[i][j] = (f32x4){0.f, 0.f, 0.f, 0.f};

    int fr = lane & 15;
    int q8 = (((lane >> 4) ^ ((fr >> 1) & 3)) << 3);      // swizzled read chunk

    for (int k0 = 0; k0 < K; k0 += 32) {
        gload16(Ahi + aoff0 + k0, lA0);
        gload16(Ahi + aoff1 + k0, lA1);
        gload16(Alo + aoff0 + k0, lAl0);
        gload16(Alo + aoff1 + k0, lAl1);
        gload16(Bhi + boff0 + k0, lB0);
        gload16(Bhi + boff1 + k0, lB1);
        gload16(Blo + boff0 + k0, lBl0);
        gload16(Blo + boff1 + k0, lBl1);
        __syncthreads();

        bf16x8 ah[4], al[4], bh[4], bl[4];
        #pragma unroll
        for (int t = 0; t < 4; t++) {
            ah[t] = *(const bf16x8*)&sAh[(wm * 64 + t * 16 + fr) * 32 + q8];
            al[t] = *(const bf16x8*)&sAl[(wm * 64 + t * 16 + fr) * 32 + q8];
            bh[t] = *(const bf16x8*)&sBh[(wn * 64 + t * 16 + fr) * 32 + q8];
            bl[t] = *(const bf16x8*)&sBl[(wn * 64 + t * 16 + fr) * 32 + q8];
        }
        #pragma unroll
        for (int i = 0; i < 4; i++)
            #pragma unroll
            for (int j = 0; j < 4; j++) {
                acc[i][j] = __builtin_amdgcn_mfma_f32_16x16x32_bf16(ah[i], bh[j], acc[i][j], 0, 0, 0);
                acc[i][j] = __builtin_amdgcn_mfma_f32_16x16x32_bf16(al[i], bh[j], acc[i][j], 0, 0, 0);
                acc[i][j] = __builtin_amdgcn_mfma_f32_16x16x32_bf16(ah[i], bl[j], acc[i][j], 0, 0, 0);
            }
        __syncthreads();
    }

    int q4 = (lane >> 4) * 4, c16 = lane & 15;
    #pragma unroll
    for (int i = 0; i < 4; i++)
        #pragma unroll
        for (int j = 0; j < 4; j++) {
            f32x4 v = acc[i][j];
            int col = bn + wn * 64 + j * 16 + c16;
            #pragma unroll
            for (int r = 0; r < 4; r++) {
                int row = bm + wm * 64 + i * 16 + q4 + r;
                float val = v[r];
                if (mode == 0) {
                    Cf[(size_t)z * (1024 * 1024) + (size_t)row * 1024 + col] = val * 0.0625f;
                } else {
                    size_t o = ((size_t)((g >> 3) * 1024 + row)) * 2048 + (size_t)(g & 7) * 256 + col;
                    unsigned short hv = f2bf(val);
                    Ohi[o] = hv;
                    Olo[o] = f2bf(val - bf2f(hv));
                }
            }
        }
}

// ---------------- row softmax, in-place f32 -> bf16 hi/lo ----------------
__global__ __launch_bounds__(256) void softmax_rows(float* __restrict__ S)
{
    int lane = threadIdx.x & 63, wid = threadIdx.x >> 6;
    size_t row = (size_t)blockIdx.x * 4 + wid;
    float* rp = S + row * 1024;

    float4 x[4];
    float m = -1e30f;
    #pragma unroll
    for (int w = 0; w < 4; w++) {
        x[w] = *(const float4*)&rp[w * 256 + lane * 4];
        m = fmaxf(m, fmaxf(fmaxf(x[w].x, x[w].y), fmaxf(x[w].z, x[w].w)));
    }
    #pragma unroll
    for (int off = 1; off < 64; off <<= 1) m = fmaxf(m, __shfl_xor(m, off));

    float s = 0.f;
    #pragma unroll
    for (int w = 0; w < 4; w++) {
        x[w].x = __expf(x[w].x - m);
        x[w].y = __expf(x[w].y - m);
        x[w].z = __expf(x[w].z - m);
        x[w].w = __expf(x[w].w - m);
        s += x[w].x + x[w].y + x[w].z + x[w].w;
    }
    #pragma unroll
    for (int off = 1; off < 64; off <<= 1) s += __shfl_xor(s, off);
    float inv = 1.f / s;

    unsigned short* hp = (unsigned short*)rp;
    unsigned short* lp = hp + 1024;
    #pragma unroll
    for (int w = 0; w < 4; w++) {
        float a0 = x[w].x * inv, a1 = x[w].y * inv;
        float a2 = x[w].z * inv, a3 = x[w].w * inv;
        ushort4 h, l;
        h.x = f2bf(a0); l.x = f2bf(a0 - bf2f(h.x));
        h.y = f2bf(a1); l.y = f2bf(a1 - bf2f(h.y));
        h.z = f2bf(a2); l.z = f2bf(a2 - bf2f(h.z));
        h.w = f2bf(a3); l.w = f2bf(a3 - bf2f(h.w));
        int c = w * 256 + lane * 4;
        *(ushort4*)&hp[c] = h;
        *(ushort4*)&lp[c] = l;
    }
}

// ---------------- fp32 GEMM (small shapes) ----------------
#define BM 64
#define BN 64
#define BK 16
__global__ __launch_bounds__(256) void gemm_f32(
    const float* __restrict__ A, const float* __restrict__ B,
    const float* __restrict__ bias, float* __restrict__ C,
    int M, int N, int K, int lda, int ldb, int ldc, int flags)
{
    __shared__ float As[BK][BM + 4];
    __shared__ float Bs[BK][BN + 4];
    int tid = threadIdx.x;
    int tm = tid >> 4, tn = tid & 15;
    int bm = blockIdx.y * BM, bn = blockIdx.x * BN;
    float acc[4][4] = {};

    for (int k0 = 0; k0 < K; k0 += BK) {
        #pragma unroll
        for (int i = 0; i < 4; i++) {
            int idx = tid + i * 256;
            int r = idx >> 4, c = idx & 15;
            int gr = bm + r, gc = k0 + c;
            float v = 0.f;
            if (gr < M && gc < K) v = A[(size_t)gr * lda + gc];
            As[c][r] = v;
        }
        #pragma unroll
        for (int i = 0; i < 4; i++) {
            int idx = tid + i * 256;
            int r = idx >> 6, c = idx & 63;
            int gr = k0 + r, gc = bn + c;
            float v = 0.f;
            if (gr < K && gc < N) v = B[(size_t)gr * ldb + gc];
            Bs[r][c] = v;
        }
        __syncthreads();
        #pragma unroll
        for (int kk = 0; kk < BK; kk++) {
            float4 a4 = *(const float4*)&As[kk][tm * 4];
            float4 b4 = *(const float4*)&Bs[kk][tn * 4];
            float av[4] = {a4.x, a4.y, a4.z, a4.w};
            float bv[4] = {b4.x, b4.y, b4.z, b4.w};
            #pragma unroll
            for (int i = 0; i < 4; i++)
                #pragma unroll
                for (int j = 0; j < 4; j++)
                    acc[i][j] += av[i] * bv[j];
        }
        __syncthreads();
    }

    #pragma unroll
    for (int i = 0; i < 4; i++) {
        int row = bm + tm * 4 + i;
        if (row >= M) continue;
        #pragma unroll
        for (int j = 0; j < 4; j++) {
            int col = bn + tn * 4 + j;
            if (col >= N) continue;
            float val = acc[i][j];
            if (flags & FLAG_BIAS) val += bias[col];
            if (flags & FLAG_SOFTPLUS) val = (val > 20.f) ? val : log1pf(__expf(val));
            C[(size_t)row * ldc + col] = val;
        }
    }
}

// ---------------- BC repack: dbc[row][128+n],[144+n] -> interleaved pairs at cols 0..31 ----------------
__global__ __launch_bounds__(256) void repack_bc(float* __restrict__ dbc)
{
    int i = blockIdx.x * 256 + threadIdx.x;   // 0 .. 8192*16-1
    int n = i & 15;
    int row = i >> 4;
    float B = dbc[(size_t)row * 160 + DTRANK + n];
    float C = dbc[(size_t)row * 160 + DTRANK + DSTATE + n];
    float2 p; p.x = B; p.y = C;
    ((float2*)&dbc[(size_t)row * 160])[n] = p;
}

// ---------------- conv+silu transpose: x[t][d] -> xsT[b][d][t] ----------------
// grid (64 d-tiles, 128 t-tiles), 256 threads, 64x64 tile
__global__ __launch_bounds__(256) void conv_prep(
    const float* __restrict__ xz, float* __restrict__ xsT,
    const float* __restrict__ conv_w, const float* __restrict__ conv_b)
{
    __shared__ float sx[67][68];
    int tid = threadIdx.x;
    int d0 = blockIdx.x * 64;
    int t0 = blockIdx.y * 64;           // global row index (b*1024 + tloc)
    int tloc0 = t0 & 1023;

    // load rows t0-3 .. t0+63 (67 rows x 64 d), zero halo at sequence start
    int lr = tid >> 2;                  // 0..63
    int lc = (tid & 3) * 16;            // 0,16,32,48
    for (int rr = lr; rr < 67; rr += 64) {
        int tg = t0 - 3 + rr;
        bool ok = (tloc0 != 0) || (rr >= 3);
        #pragma unroll
        for (int c = 0; c < 16; c += 4) {
            float4 v = ok ? *(const float4*)&xz[(size_t)tg * 8192 + d0 + lc + c]
                          : (float4){0.f, 0.f, 0.f, 0.f};
            *(float4*)&sx[rr][lc + c] = v;
        }
    }
    __syncthreads();

    // compute: thread -> d = d0 + (tid>>2), t quarter = (tid&3)*16
    int dr = tid >> 2;
    int tq = (tid & 3) * 16;
    int d = d0 + dr;
    float cw0 = conv_w[d * 4 + 0], cw1 = conv_w[d * 4 + 1];
    float cw2 = conv_w[d * 4 + 2], cw3 = conv_w[d * 4 + 3];
    float cb = conv_b[d];

    float x0 = sx[tq + 0][dr], x1 = sx[tq + 1][dr], x2 = sx[tq + 2][dr];
    float o[16];
    #pragma unroll
    for (int tt = 0; tt < 16; tt++) {
        float x3 = sx[tq + tt + 3][dr];
        float xc = cw0 * x0 + cw1 * x1 + cw2 * x2 + cw3 * x3 + cb;
        o[tt] = fsilu(xc);
        x0 = x1; x1 = x2; x2 = x3;
    }
    size_t ob = ((size_t)(t0 >> 10) * 4096 + d) * 1024 + tloc0 + tq;
    #pragma unroll
    for (int c = 0; c < 16; c += 4)
        *(float4*)&xsT[ob + c] = (float4){o[c], o[c+1], o[c+2], o[c+3]};
}

// ---------------- lean mamba scan (transposed streams, LDS chunked) ----------------
// xsT/dtT: f32 [8][4096][1024]; bc: packed (B,C) pairs at dbc cols 0..31.
// writes y' = p + dsk*xs (pre-gate) into xz x-cols [t][d].
__global__ __launch_bounds__(256) void mamba_scan(
    float* __restrict__ xz, const float* __restrict__ dtT,
    const float* __restrict__ bc, const float* __restrict__ A_log,
    const float* __restrict__ D_skip, const float* __restrict__ xsT)
{
    __shared__ float sxs[16 * 68];
    __shared__ float sdt[16 * 68];
    __shared__ float sbc[64 * 32];

    int tid = threadIdx.x;
    int n = tid & 15;
    int dd = tid >> 4;
    int gb = blockIdx.x;
    int b = gb >> 8;
    int d0 = (gb & 255) << 4;
    int d = d0 + dd;

    float A_n = -__expf(A_log[d * DSTATE + n]);
    float dsk = D_skip[d];
    float h = 0.f;

    size_t baseT = ((size_t)b * 4096 + d0) * 1024;
    size_t rowbc = (size_t)b * SEQ * 160;
    size_t rowx  = (size_t)b * SEQ * 8192 + d;

    int sr = tid >> 4;            // 0..15: d-row for xs/dt staging
    int sc = (tid & 15) * 4;      // float4 col
    int br = tid >> 2;            // 0..63: t-row for bc staging
    int bq = (tid & 3) * 8;

    for (int t0 = 0; t0 < SEQ; t0 += 64) {
        float4 vx = *(const float4*)&xsT[baseT + (size_t)sr * 1024 + t0 + sc];
        float4 vd = *(const float4*)&dtT[baseT + (size_t)sr * 1024 + t0 + sc];
        float4 v0 = *(const float4*)&bc[rowbc + (size_t)(t0 + br) * 160 + bq];
        float4 v1 = *(const float4*)&bc[rowbc + (size_t)(t0 + br) * 160 + bq + 4];
        __syncthreads();
        *(float4*)&sxs[sr * 68 + sc] = vx;
        *(float4*)&sdt[sr * 68 + sc] = vd;
        *(float4*)&sbc[br * 32 + bq] = v0;
        *(float4*)&sbc[br * 32 + bq + 4] = v1;
        __syncthreads();

        #pragma unroll 4
        for (int tl = 0; tl < 64; tl++) {
            float xv  = sxs[dd * 68 + tl];
            float dtv = sdt[dd * 68 + tl];
            float2 bcv = *(const float2*)&sbc[tl * 32 + 2 * n];
            float dA = __expf(dtv * A_n);
            h = dA * h + (dtv * xv) * bcv.x;
            float p = h * bcv.y;
            p = dppadd<0xB1>(p);    // quad_perm xor1
            p = dppadd<0x4E>(p);    // quad_perm xor2
            p = dppadd<0x141>(p);   // row_half_mirror
            p = dppadd<0x140>(p);   // row_mirror
            if (n == 0)
                xz[rowx + (size_t)(t0 + tl) * 8192] = p + dsk * xv;
        }
    }
}

// ---------------- launcher ----------------
extern "C" void kernel_launch(void* const* d_in, const int* in_sizes, int n_in,
                              void* d_out, int out_size, void* d_ws, size_t ws_size,
                              hipStream_t stream) {
    const float* imgF   = (const float*)d_in[0];
    const float* kf     = (const float*)d_in[1];
    const float* Wq     = (const float*)d_in[2];
    const float* bq     = (const float*)d_in[3];
    const float* Wk     = (const float*)d_in[4];
    const float* bk     = (const float*)d_in[5];
    const float* Wv     = (const float*)d_in[6];
    const float* bv     = (const float*)d_in[7];
    const float* Wo     = (const float*)d_in[8];
    const float* bo     = (const float*)d_in[9];
    const float* W_in   = (const float*)d_in[10];
    const float* conv_w = (const float*)d_in[11];
    const float* conv_b = (const float*)d_in[12];
    const float* W_extra= (const float*)d_in[13];
    const float* W_xproj= (const float*)d_in[14];
    const float* W_dt   = (const float*)d_in[15];
    const float* b_dt   = (const float*)d_in[16];
    const float* A_log  = (const float*)d_in[17];
    const float* D_skip = (const float*)d_in[18];
    const float* W_out  = (const float*)d_in[19];
    float* out = (float*)d_out;
    char* W = (char*)d_ws;

    #define WS_F(off) ((float*)(W + (off)))
    #define WS_U(off) ((unsigned short*)(W + (off)))

    dim3 blk(256);
    auto gg = [](int M, int N) { return dim3((N + BN - 1) / BN, (M + BM - 1) / BM); };

    // ===== mamba phase =====
    // imgF -> bf16 hi/lo
    cvt_hilo<<<dim3(16384), blk, 0, stream>>>(imgF, WS_U(O_IMGH), WS_U(O_IMGL), 4194304);
    // W_in (2048x8192) -> W_in^T hi/lo
    tcvt<<<dim3(8192/32, 2048/32), blk, 0, stream>>>(W_in, WS_U(O_WINTH), WS_U(O_WINTL), 2048, 8192);
    // xz = imgF @ W_in   (M=8192, N=8192, K=2048)
    gemm_mfma3<<<dim3(64, 64), blk, 0, stream>>>(WS_U(O_IMGH), WS_U(O_IMGL),
        WS_U(O_WINTH), WS_U(O_WINTL), nullptr, WS_F(O_XZ), nullptr, nullptr,
        8192, 8192, 2048, 0);
    // Wcomb = W_extra @ W_xproj   (2048x160, K=4096)
    gemm_f32<<<gg(2048, 160), blk, 0, stream>>>(W_extra, W_xproj, nullptr, WS_F(O_WCOMB),
        2048, 160, 4096, 4096, 160, 160, 0);
    // dbc = kf @ Wcomb
    gemm_f32<<<gg(8192, 160), blk, 0, stream>>>(kf, WS_F(O_WCOMB), nullptr, WS_F(O_DBC),
        8192, 160, 2048, 2048, 160, 160, 0);
    // pack dbc dt-rank cols -> bf16 hi/lo (imgh region is dead now)
    pack_dbc128<<<dim3(1024), blk, 0, stream>>>(WS_F(O_DBC), WS_U(O_DBCH), WS_U(O_DBCL));
    // pack (B,C) pairs into dead dt-rank cols of dbc
    repack_bc<<<dim3(512), blk, 0, stream>>>(WS_F(O_DBC));
    // W_dt (128x4096) -> W_dt^T hi/lo
    tcvt<<<dim3(4096/32, 128/32), blk, 0, stream>>>(W_dt, WS_U(O_WDTH), WS_U(O_WDTL), 128, 4096);
    // dtT = softplus(dbc128 @ W_dt + b_dt) transposed [b][d][t] -> d_out
    gemm_mfma3<<<dim3(32, 64), blk, 0, stream>>>(WS_U(O_DBCH), WS_U(O_DBCL),
        WS_U(O_WDTH), WS_U(O_WDTL), b_dt, out, nullptr, nullptr,
        8192, 4096, 128, FLAG_BIAS | FLAG_DTT);
    // xsT = silu(conv(x)) transposed [b][d][t]  (clobbers dbc128/wdt copies - dead)
    conv_prep<<<dim3(64, 128), blk, 0, stream>>>(WS_F(O_XZ), WS_F(O_XST), conv_w, conv_b);
    // lean scan: y' -> xz x-cols
    mamba_scan<<<dim3(2048), blk, 0, stream>>>(WS_F(O_XZ), out, WS_F(O_DBC),
        A_log, D_skip, WS_F(O_XST));
    // y = y' * silu(z) -> bf16 hi/lo (over xsT - dead)
    ycvt<<<dim3(32768), blk, 0, stream>>>(WS_F(O_XZ), WS_U(O_YH), WS_U(O_YL));
    // W_out (4096x2048) -> W_out^T hi/lo (xz dead)
    tcvt<<<dim3(2048/32, 4096/32), blk, 0, stream>>>(W_out, WS_U(O_WOUTH), WS_U(O_WOUTL), 4096, 2048);
    // out1 = y @ W_out   (M=8192, N=2048, K=4096)  (dtT in d_out dead)
    gemm_mfma3<<<dim3(16, 64), blk, 0, stream>>>(WS_U(O_YH), WS_U(O_YL),
        WS_U(O_WOUTH), WS_U(O_WOUTL), nullptr, out + 16777216, nullptr, nullptr,
        8192, 2048, 4096, 0);

    // ===== attention phase =====
    cvt_hilo<<<dim3(16384), blk, 0, stream>>>(imgF, WS_U(A_IMGH), WS_U(A_IMGL), 4194304);
    tcvt<<<dim3(64, 64), blk, 0, stream>>>(Wq, WS_U(A_WQH), WS_U(A_WQL), 2048, 2048);
    tcvt<<<dim3(64, 64), blk, 0, stream>>>(Wk, WS_U(A_WKH), WS_U(A_WKL), 2048, 2048);
    tcvt<<<dim3(64, 64), blk, 0, stream>>>(Wv, WS_U(A_WVH), WS_U(A_WVL), 2048, 2048);
    tcvt<<<dim3(64, 64), blk, 0, stream>>>(Wo, WS_U(A_WOH), WS_U(A_WOL), 2048, 2048);
    // q = imgF @ Wq + bq  -> bf16 hi/lo 8192x2048
    gemm_mfma3<<<dim3(16, 64), blk, 0, stream>>>(WS_U(A_IMGH), WS_U(A_IMGL),
        WS_U(A_WQH), WS_U(A_WQL), bq, nullptr, WS_U(A_QH), WS_U(A_QL),
        8192, 2048, 2048, FLAG_BIAS | FLAG_BF16);
    // k = imgF @ Wk + bk  -> bf16 hi/lo 8192x2048 (natural layout == B^T for S)
    gemm_mfma3<<<dim3(16, 64), blk, 0, stream>>>(WS_U(A_IMGH), WS_U(A_IMGL),
        WS_U(A_WKH), WS_U(A_WKL), bk, nullptr, WS_U(A_KH), WS_U(A_KL),
        8192, 2048, 2048, FLAG_BIAS | FLAG_BF16);
    // v^T = (imgF @ Wv + bv) transposed per (b,h) -> bf16 hi/lo (b,h,dk,seq)
    gemm_mfma3<<<dim3(16, 64), blk, 0, stream>>>(WS_U(A_IMGH), WS_U(A_IMGL),
        WS_U(A_WVH), WS_U(A_WVL), bv, nullptr, WS_U(A_VTH), WS_U(A_VTL),
        8192, 2048, 2048, FLAG_BIAS | FLAG_BF16 | FLAG_KT);
    // chunked attention: 4 chunks x 16 (b,h) batches, 64 MiB score buffer
    for (int c = 0; c < 4; c++) {
        gemm_att3<<<dim3(8, 8, 16), blk, 0, stream>>>(WS_U(A_QH), WS_U(A_QL),
            WS_U(A_KH), WS_U(A_KL), WS_F(A_S), nullptr, nullptr,
            256, 2048, 2048, c * 16, 0);
        softmax_rows<<<dim3(4096), blk, 0, stream>>>(WS_F(A_S));
        gemm_att3<<<dim3(2, 8, 16), blk, 0, stream>>>(
            (unsigned short*)WS_F(A_S), (unsigned short*)WS_F(A_S) + 1024,
            WS_U(A_VTH), WS_U(A_VTL), nullptr, WS_U(A_ATTH), WS_U(A_ATTL),
            1024, 2048, 1024, c * 16, 1);
    }
    // out0 = att @ Wo + bo
    gemm_mfma3<<<dim3(16, 64), blk, 0, stream>>>(WS_U(A_ATTH), WS_U(A_ATTL),
        WS_U(A_WOH), WS_U(A_WOL), bo, out, nullptr, nullptr,
        8192, 2048, 2048, FLAG_BIAS);
}